// Round 20
// baseline (398.740 us; speedup 1.0000x reference)
//
#include <hip/hip_runtime.h>

#define NN 3072
#define FIN 1546
#define KP 1568          // FIN padded to multiple of 32
#define MAXR 192         // max CSR nnz/row (measured mean ~61)

#define XSPLIT_BLOCKS (NN * KP / 256)      // 18816
#define WSPLIT_BLOCKS (256 * KP / 256)     // 1568
#define CSR_BLOCKS (NN / 4)                // 768

typedef __attribute__((ext_vector_type(8))) __bf16 bf16x8;
typedef __attribute__((ext_vector_type(4))) float f32x4;

// ---- fused prep: [0,XS) xsplit ; [XS,XS+WS) wsplit ; rest csr build ----
__global__ __launch_bounds__(256) void prep_k(const float* __restrict__ adj,
                                              int* __restrict__ cols, float* __restrict__ vals,
                                              int* __restrict__ cnt, float* __restrict__ dvec,
                                              const float* __restrict__ X,
                                              __bf16* __restrict__ Xh, __bf16* __restrict__ Xl,
                                              const float* __restrict__ W,
                                              __bf16* __restrict__ WhT, __bf16* __restrict__ WlT) {
    int bid = blockIdx.x;
    if (bid < XSPLIT_BLOCKS) {
        int idx = bid * 256 + threadIdx.x;
        int i = idx / KP, c = idx - i * KP;
        float x = (c < FIN) ? X[(size_t)i * FIN + c] : 0.f;
        __bf16 h = (__bf16)x;
        Xh[idx] = h;
        Xl[idx] = (__bf16)(x - (float)h);
        return;
    }
    bid -= XSPLIT_BLOCKS;
    if (bid < WSPLIT_BLOCKS) {
        int idx = bid * 256 + threadIdx.x;
        int c = idx / KP, k = idx - c * KP;
        float x = (k < FIN) ? W[(size_t)k * 256 + c] : 0.f;
        __bf16 h = (__bf16)x;
        WhT[idx] = h;
        WlT[idx] = (__bf16)(x - (float)h);
        return;
    }
    bid -= WSPLIT_BLOCKS;
    int i = bid * 4 + (threadIdx.x >> 6);
    int lane = threadIdx.x & 63;
    const float* row = adj + (size_t)i * NN;
    float s = 0.f; int count = 0;
    int base = i * MAXR;
    for (int c = 0; c < NN; c += 64) {
        float a = row[c + lane];
        s += a;
        unsigned long long m = __ballot(a != 0.f);
        if (a != 0.f) {
            int pos = count + __popcll(m & ((1ull << lane) - 1ull));
            if (pos < MAXR) { cols[base + pos] = c + lane; vals[base + pos] = a; }
        }
        count += __popcll(m);
    }
    for (int off = 32; off; off >>= 1) s += __shfl_xor(s, off);
    if (lane == 0) {
        cnt[i] = count < MAXR ? count : MAXR;
        dvec[i] = (s > 0.f) ? 1.0f / sqrtf(s) : 0.f;
    }
}

// ---- fc1 MFMA, no split-K: 32x64 tile, 2 waves, fused bias+relu -> X0 ----
__global__ __launch_bounds__(128) void fc1m_k(const __bf16* __restrict__ Xh,
                                              const __bf16* __restrict__ Xl,
                                              const __bf16* __restrict__ WhT,
                                              const __bf16* __restrict__ WlT,
                                              const float* __restrict__ bias,
                                              float* __restrict__ X0) {
    int tid = threadIdx.x;
    int w = tid >> 6, lane = tid & 63;
    int m = lane & 15, q = lane >> 4;
    int i0 = blockIdx.x * 32, c0 = blockIdx.y * 64;
    int rowA = i0 + w * 16 + m;
    const __bf16* xh = Xh + (size_t)rowA * KP + q * 8;
    const __bf16* xl = Xl + (size_t)rowA * KP + q * 8;
    const __bf16* bh0 = WhT + (size_t)(c0 + m) * KP + q * 8;
    const __bf16* bl0 = WlT + (size_t)(c0 + m) * KP + q * 8;

    f32x4 acc[4];
    #pragma unroll
    for (int ct = 0; ct < 4; ct++)
        #pragma unroll
        for (int r = 0; r < 4; r++) acc[ct][r] = 0.f;

    for (int ks = 0; ks < KP; ks += 32) {
        bf16x8 ah = *(const bf16x8*)(xh + ks);
        bf16x8 al = *(const bf16x8*)(xl + ks);
        #pragma unroll
        for (int ct = 0; ct < 4; ct++) {
            bf16x8 bh = *(const bf16x8*)(bh0 + (size_t)ct * 16 * KP + ks);
            bf16x8 bl = *(const bf16x8*)(bl0 + (size_t)ct * 16 * KP + ks);
            acc[ct] = __builtin_amdgcn_mfma_f32_16x16x32_bf16(ah, bh, acc[ct], 0, 0, 0);
            acc[ct] = __builtin_amdgcn_mfma_f32_16x16x32_bf16(ah, bl, acc[ct], 0, 0, 0);
            acc[ct] = __builtin_amdgcn_mfma_f32_16x16x32_bf16(al, bh, acc[ct], 0, 0, 0);
        }
    }
    int rowBase = i0 + w * 16 + q * 4;
    #pragma unroll
    for (int ct = 0; ct < 4; ct++) {
        int col = c0 + ct * 16 + m;
        float bc = bias[col];
        #pragma unroll
        for (int r = 0; r < 4; r++)
            X0[(size_t)(rowBase + r) * 256 + col] = fmaxf(acc[ct][r] + bc, 0.f);
    }
}

// ---- merged mask builder: y=0,1 -> threshold masks; y=2 -> An^2 sparse x sparse ----
__global__ __launch_bounds__(256) void maskall_k(const int* __restrict__ cols,
                                                 const float* __restrict__ vals,
                                                 const int* __restrict__ cnt,
                                                 const float* __restrict__ dvec,
                                                 const float* __restrict__ thrp,
                                                 int* __restrict__ mcols,
                                                 float* __restrict__ mvals,
                                                 int* __restrict__ mcnt,
                                                 float* __restrict__ db) {
    __shared__ float ds[NN];
    __shared__ int lcols[MAXR];
    __shared__ float lvals[MAXR];
    __shared__ int lcnt;
    __shared__ float osum;
    int i = blockIdx.x, tid = threadIdx.x, mode = blockIdx.y;
    mcols += (size_t)mode * NN * MAXR;
    mvals += (size_t)mode * NN * MAXR;
    mcnt  += (size_t)mode * NN;
    db    += (size_t)mode * NN;
    int ni = cnt[i], base = i * MAXR;
    float thr = *thrp;
    float di = dvec[i];

    if (mode < 2) {
        if (tid == 0) lcnt = 0;
        __syncthreads();
        float s = 0.f;
        if (tid < ni) {
            int j = cols[base + tid];
            float a = vals[base + tid];
            float m = (mode == 0) ? a : a * di * dvec[j];
            if (m > thr) {
                int p = atomicAdd(&lcnt, 1);
                mcols[base + p] = j;
                mvals[base + p] = a;
                s = a;
            }
        }
        ds[tid] = s; __syncthreads();
        for (int off = 128; off; off >>= 1) {
            if (tid < off) ds[tid] += ds[tid + off];
            __syncthreads();
        }
        if (tid == 0) {
            mcnt[i] = lcnt;
            db[i] = 1.0f / sqrtf(ds[0] + 1.0f);
        }
        return;
    }

    if (tid == 0) { osum = 0.f; lcnt = 0; }
    for (int j = tid; j < NN; j += 256) ds[j] = 0.f;
    __syncthreads();
    for (int t = tid; t < ni; t += 256) {
        int j = cols[base + t];
        float a = vals[base + t];
        lcols[t] = j; lvals[t] = a;
        ds[j] = a * dvec[j] * dvec[j];
    }
    __syncthreads();
    int lane = tid & 63, wv = tid >> 6;
    int sub = lane & 15, dg = lane >> 4;      // 16-lane subgroup, 4 dots/wave in flight
    for (int o = wv * 4 + dg; o < ni; o += 16) {
        int j = lcols[o];
        int nj = cnt[j], bj = j * MAXR;
        float dot = 0.f;
        for (int t = sub; t < nj; t += 16)
            dot += vals[bj + t] * ds[cols[bj + t]];
        #pragma unroll
        for (int off = 8; off; off >>= 1) dot += __shfl_xor(dot, off);
        if (sub == 0 && di * dvec[j] * dot > thr) {
            int p = atomicAdd(&lcnt, 1);
            mcols[base + p] = j;
            mvals[base + p] = lvals[o];
            atomicAdd(&osum, lvals[o]);
        }
    }
    __syncthreads();
    if (tid == 0) {
        mcnt[i] = lcnt;
        db[i] = 1.0f / sqrtf(osum + 1.0f);
    }
}

// ---- branch-batched GEMM: 64x64 tile, 4x4/thread; z = branch; N=128 ----
__global__ __launch_bounds__(256) void gemm3_k(const float* __restrict__ A, int aplane, int lda,
                                               const float* __restrict__ B0,
                                               const float* __restrict__ B1,
                                               const float* __restrict__ B2,
                                               int K, float* __restrict__ out) {
    __shared__ float Ast[16][68];
    __shared__ float Bs[16][64];
    int tid = threadIdx.x;
    int tx = tid & 15, ty = tid >> 4;
    int i0 = blockIdx.x * 64, c0 = blockIdx.y * 64;
    int z = blockIdx.z;
    const float* Ab = A + (size_t)z * aplane;
    const float* B = (z == 0) ? B0 : (z == 1) ? B1 : B2;
    float* outp = out + (size_t)z * NN * 128;
    int sr = tid >> 4, sk = tid & 15;
    int bk = tid >> 4, bc4 = (tid & 15) << 2;

    float ap[4]; float4 bp;
    #pragma unroll
    for (int u = 0; u < 4; u++) ap[u] = Ab[(size_t)(i0 + sr + u * 16) * lda + sk];
    bp = *(const float4*)&B[(size_t)bk * 128 + c0 + bc4];

    float acc[4][4];
    #pragma unroll
    for (int r = 0; r < 4; r++)
        #pragma unroll
        for (int c = 0; c < 4; c++) acc[r][c] = 0.f;

    for (int kt = 0; kt < K; kt += 16) {
        __syncthreads();
        #pragma unroll
        for (int u = 0; u < 4; u++) Ast[sk][sr + u * 16] = ap[u];
        *(float4*)&Bs[bk][bc4] = bp;
        __syncthreads();
        int kn = kt + 16;
        if (kn < K) {
            #pragma unroll
            for (int u = 0; u < 4; u++) ap[u] = Ab[(size_t)(i0 + sr + u * 16) * lda + kn + sk];
            bp = *(const float4*)&B[(size_t)(kn + bk) * 128 + c0 + bc4];
        }
        #pragma unroll
        for (int kk = 0; kk < 16; kk++) {
            float4 a = *(const float4*)&Ast[kk][ty * 4];
            float4 b = *(const float4*)&Bs[kk][tx * 4];
            const float* av = (const float*)&a;
            const float* bv = (const float*)&b;
            #pragma unroll
            for (int r = 0; r < 4; r++)
                #pragma unroll
                for (int c = 0; c < 4; c++) acc[r][c] += av[r] * bv[c];
        }
    }
    #pragma unroll
    for (int r = 0; r < 4; r++) {
        int row = i0 + ty * 4 + r;
        float4 v = make_float4(acc[r][0], acc[r][1], acc[r][2], acc[r][3]);
        *(float4*)&outp[(size_t)row * 128 + c0 + tx * 4] = v;
    }
}

// ---- SpMM: masked CSR, float4 gather, 8-way t-parallel ----
__global__ __launch_bounds__(256) void spmm3_k(const int* __restrict__ mcols,
                                               const float* __restrict__ mvals,
                                               const int* __restrict__ mcnt,
                                               const float* __restrict__ db,
                                               const float* __restrict__ Xin,   // [3][NN][128]
                                               const float* __restrict__ bias0,
                                               const float* __restrict__ bias1,
                                               const float* __restrict__ bias2,
                                               float* __restrict__ outA,        // [3][NN][128] or null
                                               float* __restrict__ embf, int coff) {
    __shared__ float lcoef[MAXR];
    __shared__ int lj[MAXR];
    __shared__ float4 part[8][32];
    int i = blockIdx.x, tid = threadIdx.x, b = blockIdx.y;
    mcols += (size_t)b * NN * MAXR;
    mvals += (size_t)b * NN * MAXR;
    mcnt  += (size_t)b * NN;
    db    += (size_t)b * NN;
    const float* Xb = Xin + (size_t)b * NN * 128;
    const float* bias = (b == 0) ? bias0 : (b == 1) ? bias1 : bias2;
    float dbi = db[i];
    int n = mcnt[i], base = i * MAXR;
    if (tid < n) {
        int j = mcols[base + tid];
        lj[tid] = j;
        lcoef[tid] = mvals[base + tid] * dbi * db[j];
    }
    __syncthreads();
    int g = tid >> 5, c4 = (tid & 31) << 2;
    float4 acc = make_float4(0.f, 0.f, 0.f, 0.f);
    if (g == 0) {
        float4 x = *(const float4*)&Xb[(size_t)i * 128 + c4];
        float d2 = dbi * dbi;
        acc = make_float4(d2 * x.x, d2 * x.y, d2 * x.z, d2 * x.w);
    }
    for (int t = g; t < n; t += 8) {
        float cf = lcoef[t];
        float4 x = *(const float4*)&Xb[(size_t)lj[t] * 128 + c4];
        acc.x += cf * x.x; acc.y += cf * x.y; acc.z += cf * x.z; acc.w += cf * x.w;
    }
    part[g][tid & 31] = acc;
    __syncthreads();
    if (tid < 32) {
        float4 s = part[0][tid];
        #pragma unroll
        for (int gg = 1; gg < 8; gg++) {
            float4 t4 = part[gg][tid];
            s.x += t4.x; s.y += t4.y; s.z += t4.z; s.w += t4.w;
        }
        int cc = tid << 2;
        float4 bv = *(const float4*)&bias[cc];
        s.x = fmaxf(s.x + bv.x, 0.f); s.y = fmaxf(s.y + bv.y, 0.f);
        s.z = fmaxf(s.z + bv.z, 0.f); s.w = fmaxf(s.w + bv.w, 0.f);
        if (outA) *(float4*)&outA[((size_t)b * NN + i) * 128 + cc] = s;
        *(float4*)&embf[((size_t)b * NN + i) * 256 + coff + cc] = s;
    }
}

// ---- dilated 3x3 conv: LDS-staged rows, one block per output row n ----
__global__ __launch_bounds__(256) void conv3f_k(const float* __restrict__ emb,
                                                const float* __restrict__ ck,
                                                const float* __restrict__ cb,
                                                float* __restrict__ outf) {
    __shared__ float rows[3][3][256];
    int n = blockIdx.x, c = threadIdx.x;
    #pragma unroll
    for (int i = 0; i < 3; i++)
        #pragma unroll
        for (int kh = 0; kh < 3; kh++) {
            int nn2 = n + 2 * kh - 2;
            rows[i][kh][c] = (nn2 >= 0 && nn2 < NN) ? emb[((size_t)i * NN + nn2) * 256 + c] : 0.f;
        }
    __syncthreads();
    float s = cb[0];
    #pragma unroll
    for (int i = 0; i < 3; i++)
        #pragma unroll
        for (int kh = 0; kh < 3; kh++)
            #pragma unroll
            for (int kw = 0; kw < 3; kw++) {
                int cc = c + 2 * kw - 2;
                if (cc >= 0 && cc < 256)
                    s += rows[i][kh][cc] * ck[(i * 3 + kh) * 3 + kw];
            }
    outf[(size_t)n * 256 + c] = s;
}

// ---- uv GEMM: uv[node][c] c<64: emb.Wa_left ; c>=64: emb.Wa_right. K-split 2 planes ----
__global__ __launch_bounds__(256) void gemmUV_k(const float* __restrict__ A,   // [NN][256] emb_all
                                                const float* __restrict__ Wa,  // [512][64]
                                                float* __restrict__ uvp) {     // [2][NN][128]
    __shared__ float Ast[16][68];
    __shared__ float Bs[16][64];
    int tid = threadIdx.x;
    int tx = tid & 15, ty = tid >> 4;
    int i0 = blockIdx.x * 64;
    int half = blockIdx.y;
    int z = blockIdx.z;
    int ks = z * 128;
    const float* Bb = Wa + (half ? 256 * 64 : 0);
    int sr = tid >> 4, sk = tid & 15;
    int bk = tid >> 4, bc4 = (tid & 15) << 2;

    float ap[4]; float4 bp;
    #pragma unroll
    for (int u = 0; u < 4; u++) ap[u] = A[(size_t)(i0 + sr + u * 16) * 256 + ks + sk];
    bp = *(const float4*)&Bb[(size_t)(ks + bk) * 64 + bc4];

    float acc[4][4];
    #pragma unroll
    for (int r = 0; r < 4; r++)
        #pragma unroll
        for (int c = 0; c < 4; c++) acc[r][c] = 0.f;

    for (int kt = ks; kt < ks + 128; kt += 16) {
        __syncthreads();
        #pragma unroll
        for (int u = 0; u < 4; u++) Ast[sk][sr + u * 16] = ap[u];
        *(float4*)&Bs[bk][bc4] = bp;
        __syncthreads();
        int kn = kt + 16;
        if (kn < ks + 128) {
            #pragma unroll
            for (int u = 0; u < 4; u++) ap[u] = A[(size_t)(i0 + sr + u * 16) * 256 + kn + sk];
            bp = *(const float4*)&Bb[(size_t)(kn + bk) * 64 + bc4];
        }
        #pragma unroll
        for (int kk = 0; kk < 16; kk++) {
            float4 a = *(const float4*)&Ast[kk][ty * 4];
            float4 b = *(const float4*)&Bs[kk][tx * 4];
            const float* av = (const float*)&a;
            const float* bv = (const float*)&b;
            #pragma unroll
            for (int r = 0; r < 4; r++)
                #pragma unroll
                for (int c = 0; c < 4; c++) acc[r][c] += av[r] * bv[c];
        }
    }
    float* outp = uvp + (size_t)z * NN * 128;
    #pragma unroll
    for (int r = 0; r < 4; r++) {
        int row = i0 + ty * 4 + r;
        float4 v = make_float4(acc[r][0], acc[r][1], acc[r][2], acc[r][3]);
        *(float4*)&outp[(size_t)row * 128 + half * 64 + tx * 4] = v;
    }
}

// ---- pair gather + logits: 16 pairs/block, 4 per wave ----
__global__ __launch_bounds__(256) void pairuv_k(const int* __restrict__ left,
                                                const int* __restrict__ right,
                                                const float* __restrict__ uvp,
                                                const float* __restrict__ ba,
                                                const float* __restrict__ Wb,
                                                const float* __restrict__ bb,
                                                float* __restrict__ out) {
    int tid = threadIdx.x;
    int w = tid >> 6, c = tid & 63;
    int base = blockIdx.x * 16 + w * 4;
    const float* u0 = uvp;
    const float* u1 = uvp + (size_t)NN * 128;
    float bac = ba[c];
    float w0 = Wb[c * 2], w1 = Wb[c * 2 + 1];
    float b0 = bb[0], b1 = bb[1];
    #pragma unroll
    for (int pp = 0; pp < 4; pp++) {
        int row = base + pp;
        int l = left[row], r = right[row];
        float h = u0[(size_t)l * 128 + c] + u1[(size_t)l * 128 + c]
                + u0[(size_t)r * 128 + 64 + c] + u1[(size_t)r * 128 + 64 + c] + bac;
        h = fmaxf(h, 0.f);
        float s0 = h * w0, s1 = h * w1;
        for (int off = 32; off; off >>= 1) {
            s0 += __shfl_xor(s0, off);
            s1 += __shfl_xor(s1, off);
        }
        if (c == 0) {
            out[row * 2]     = s0 + b0;
            out[row * 2 + 1] = s1 + b1;
        }
    }
}

extern "C" void kernel_launch(void* const* d_in, const int* in_sizes, int n_in,
                              void* d_out, int out_size, void* d_ws, size_t ws_size,
                              hipStream_t stream) {
    const int* left  = (const int*)d_in[0];
    const int* right = (const int*)d_in[1];
    const float* X    = (const float*)d_in[2];
    const float* adj  = (const float*)d_in[3];
    const float* thr  = (const float*)d_in[4];
    const float* Wfc1 = (const float*)d_in[5];
    const float* bfc1 = (const float*)d_in[6];
    // channel order b0,b1,b2 = (adj mask, Wg5/6), (An mask, Wg3/4), (An^2 mask, Wg1/2)
    const float* Wga[3] = { (const float*)d_in[15], (const float*)d_in[11], (const float*)d_in[7] };
    const float* bga[3] = { (const float*)d_in[16], (const float*)d_in[12], (const float*)d_in[8] };
    const float* Wgb[3] = { (const float*)d_in[17], (const float*)d_in[13], (const float*)d_in[9] };
    const float* bgb[3] = { (const float*)d_in[18], (const float*)d_in[14], (const float*)d_in[10] };
    const float* cnnk = (const float*)d_in[19];
    const float* cnnb = (const float*)d_in[20];
    const float* Wa_  = (const float*)d_in[21];
    const float* ba_  = (const float*)d_in[22];
    const float* Wb_  = (const float*)d_in[23];
    const float* bb_  = (const float*)d_in[24];

    char* p = (char*)d_ws;
    auto take = [&](size_t n) { char* q = p; p += (n + 255) & ~(size_t)255; return q; };
    float* dvec = (float*)take(NN * 4);
    float* db3  = (float*)take((size_t)3 * NN * 4);
    int*   cnt  = (int*)take(NN * 4);
    int*   mcnt3 = (int*)take((size_t)3 * NN * 4);
    int*   cols = (int*)take((size_t)NN * MAXR * 4);
    float* vals = (float*)take((size_t)NN * MAXR * 4);
    int*   mcols3 = (int*)take((size_t)3 * NN * MAXR * 4);    // 7.1 MB (contiguous with mvals3)
    float* mvals3 = (float*)take((size_t)3 * NN * MAXR * 4);  // 7.1 MB
    float* X0    = (float*)take((size_t)NN * 256 * 4);
    float* XWall = (float*)take((size_t)3 * NN * 128 * 4);
    float* e1all = (float*)take((size_t)3 * NN * 128 * 4);
    float* HW2all= (float*)take((size_t)3 * NN * 128 * 4);
    float* embf  = (float*)take((size_t)3 * NN * 256 * 4);
    __bf16* Xl   = (__bf16*)take((size_t)NN * KP * 2);        // 9.6 MB
    __bf16* WhT  = (__bf16*)take((size_t)256 * KP * 2);       // 0.8 MB
    __bf16* WlT  = (__bf16*)take((size_t)256 * KP * 2);       // 0.8 MB
    // Xh (9.6 MB) aliases mcols3+mvals3 (14.2 MB contiguous): dead once fc1m completes,
    // before maskall_k writes mcols3/mvals3.
    __bf16* Xh = (__bf16*)mcols3;
    // uvp: 2 planes of NN*128 f32 = 3.1 MB aliasing embf (dead after conv3f_k).
    float* uvp = embf;

    float* out_logits = (float*)d_out;
    float* out_emb = out_logits + 32768;

    // fused prep: xsplit + wsplit + csr build
    prep_k<<<XSPLIT_BLOCKS + WSPLIT_BLOCKS + CSR_BLOCKS, 256, 0, stream>>>(
        adj, cols, vals, cnt, dvec, X, Xh, Xl, Wfc1, WhT, WlT);

    // fc1: X0 = relu(X @ Wfc1 + b), MFMA, no split-K
    fc1m_k<<<dim3(NN / 32, 4), 128, 0, stream>>>(Xh, Xl, WhT, WlT, bfc1, X0);

    // all three branch masks in one dispatch (y=0,1 light; y=2 heavy M2)
    maskall_k<<<dim3(NN, 3), 256, 0, stream>>>(cols, vals, cnt, dvec, thr,
                                               mcols3, mvals3, mcnt3, db3);

    // XW[b] = X0 @ Wga[b]
    gemm3_k<<<dim3(NN / 64, 2, 3), 256, 0, stream>>>(X0, 0, 256, Wga[0], Wga[1], Wga[2], 256, XWall);
    // e1[b] = relu(An_b @ XW[b] + bga[b]) -> e1all + embf cols 0..127
    spmm3_k<<<dim3(NN, 3), 256, 0, stream>>>(mcols3, mvals3, mcnt3, db3, XWall,
                                             bga[0], bga[1], bga[2], e1all, embf, 0);
    // HW2[b] = e1[b] @ Wgb[b]
    gemm3_k<<<dim3(NN / 64, 2, 3), 256, 0, stream>>>(e1all, NN * 128, 128, Wgb[0], Wgb[1], Wgb[2], 128, HW2all);
    // e2[b] = relu(An_b @ HW2[b] + bgb[b]) -> embf cols 128..255
    spmm3_k<<<dim3(NN, 3), 256, 0, stream>>>(mcols3, mvals3, mcnt3, db3, HW2all,
                                             bgb[0], bgb[1], bgb[2], (float*)0, embf, 128);

    conv3f_k<<<NN, 256, 0, stream>>>(embf, cnnk, cnnb, out_emb);
    // pair MLP via u/v decomposition: uv = emb_all @ [Wa_left | Wa_right]
    gemmUV_k<<<dim3(NN / 64, 2, 2), 256, 0, stream>>>(out_emb, Wa_, uvp);
    pairuv_k<<<16384 / 16, 256, 0, stream>>>(left, right, uvp, ba_, Wb_, bb_, out_logits);
}

// Round 21
// 322.641 us; speedup vs baseline: 1.2359x; 1.2359x over previous
//
#include <hip/hip_runtime.h>

#define NN 3072
#define FIN 1546
#define KP 1568          // FIN padded to multiple of 32
#define MAXR 192         // max CSR nnz/row (measured mean ~61)
#define KSPLIT 7
#define KSLICE 224       // 7*224 = 1568

#define XSPLIT_BLOCKS (NN * KP / 256)      // 18816
#define WSPLIT_BLOCKS (256 * KP / 256)     // 1568
#define CSR_BLOCKS (NN / 4)                // 768

typedef __attribute__((ext_vector_type(8))) __bf16 bf16x8;
typedef __attribute__((ext_vector_type(4))) float f32x4;

// ---- fused prep: [0,XS) xsplit ; [XS,XS+WS) wsplit ; rest csr build ----
__global__ __launch_bounds__(256) void prep_k(const float* __restrict__ adj,
                                              int* __restrict__ cols, float* __restrict__ vals,
                                              int* __restrict__ cnt, float* __restrict__ dvec,
                                              const float* __restrict__ X,
                                              __bf16* __restrict__ Xh, __bf16* __restrict__ Xl,
                                              const float* __restrict__ W,
                                              __bf16* __restrict__ WhT, __bf16* __restrict__ WlT) {
    int bid = blockIdx.x;
    if (bid < XSPLIT_BLOCKS) {
        int idx = bid * 256 + threadIdx.x;
        int i = idx / KP, c = idx - i * KP;
        float x = (c < FIN) ? X[(size_t)i * FIN + c] : 0.f;
        __bf16 h = (__bf16)x;
        Xh[idx] = h;
        Xl[idx] = (__bf16)(x - (float)h);
        return;
    }
    bid -= XSPLIT_BLOCKS;
    if (bid < WSPLIT_BLOCKS) {
        int idx = bid * 256 + threadIdx.x;
        int c = idx / KP, k = idx - c * KP;
        float x = (k < FIN) ? W[(size_t)k * 256 + c] : 0.f;
        __bf16 h = (__bf16)x;
        WhT[idx] = h;
        WlT[idx] = (__bf16)(x - (float)h);
        return;
    }
    bid -= WSPLIT_BLOCKS;
    int i = bid * 4 + (threadIdx.x >> 6);
    int lane = threadIdx.x & 63;
    const float* row = adj + (size_t)i * NN;
    float s = 0.f; int count = 0;
    int base = i * MAXR;
    for (int c = 0; c < NN; c += 64) {
        float a = row[c + lane];
        s += a;
        unsigned long long m = __ballot(a != 0.f);
        if (a != 0.f) {
            int pos = count + __popcll(m & ((1ull << lane) - 1ull));
            if (pos < MAXR) { cols[base + pos] = c + lane; vals[base + pos] = a; }
        }
        count += __popcll(m);
    }
    for (int off = 32; off; off >>= 1) s += __shfl_xor(s, off);
    if (lane == 0) {
        cnt[i] = count < MAXR ? count : MAXR;
        dvec[i] = (s > 0.f) ? 1.0f / sqrtf(s) : 0.f;
    }
}

// ---- fc1 MFMA: 64x64 tile, 4 waves, split-K (R19-measured config) ----
__global__ __launch_bounds__(256) void fc1m_k(const __bf16* __restrict__ Xh,
                                              const __bf16* __restrict__ Xl,
                                              const __bf16* __restrict__ WhT,
                                              const __bf16* __restrict__ WlT,
                                              float* __restrict__ Cpart) {
    int tid = threadIdx.x;
    int w = tid >> 6, lane = tid & 63;
    int m = lane & 15, q = lane >> 4;
    int i0 = blockIdx.x * 64, c0 = blockIdx.y * 64;
    int z = blockIdx.z;
    int k0 = z * KSLICE;
    int rowA = i0 + w * 16 + m;
    const __bf16* xh = Xh + (size_t)rowA * KP + k0 + q * 8;
    const __bf16* xl = Xl + (size_t)rowA * KP + k0 + q * 8;
    const __bf16* bh0 = WhT + (size_t)(c0 + m) * KP + k0 + q * 8;
    const __bf16* bl0 = WlT + (size_t)(c0 + m) * KP + k0 + q * 8;

    f32x4 acc[4];
    #pragma unroll
    for (int ct = 0; ct < 4; ct++)
        #pragma unroll
        for (int r = 0; r < 4; r++) acc[ct][r] = 0.f;

    for (int ks = 0; ks < KSLICE; ks += 32) {
        bf16x8 ah = *(const bf16x8*)(xh + ks);
        bf16x8 al = *(const bf16x8*)(xl + ks);
        #pragma unroll
        for (int ct = 0; ct < 4; ct++) {
            bf16x8 bh = *(const bf16x8*)(bh0 + (size_t)ct * 16 * KP + ks);
            bf16x8 bl = *(const bf16x8*)(bl0 + (size_t)ct * 16 * KP + ks);
            acc[ct] = __builtin_amdgcn_mfma_f32_16x16x32_bf16(ah, bh, acc[ct], 0, 0, 0);
            acc[ct] = __builtin_amdgcn_mfma_f32_16x16x32_bf16(ah, bl, acc[ct], 0, 0, 0);
            acc[ct] = __builtin_amdgcn_mfma_f32_16x16x32_bf16(al, bh, acc[ct], 0, 0, 0);
        }
    }
    float* outp = Cpart + (size_t)z * NN * 256;
    int rowBase = i0 + w * 16 + q * 4;
    #pragma unroll
    for (int ct = 0; ct < 4; ct++) {
        int col = c0 + ct * 16 + m;
        #pragma unroll
        for (int r = 0; r < 4; r++)
            outp[(size_t)(rowBase + r) * 256 + col] = acc[ct][r];
    }
}

// ---- fc1 stage 2: reduce KSPLIT partials + bias + relu (float4) ----
__global__ void reduce7_k(const float* __restrict__ Cpart, const float* __restrict__ bias,
                          float* __restrict__ X0) {
    int idx4 = blockIdx.x * 256 + threadIdx.x;
    int c4 = (idx4 & 63) << 2;
    float4 s = ((const float4*)Cpart)[idx4];
    #pragma unroll
    for (int z = 1; z < KSPLIT; z++) {
        float4 t = ((const float4*)(Cpart + (size_t)z * NN * 256))[idx4];
        s.x += t.x; s.y += t.y; s.z += t.z; s.w += t.w;
    }
    float4 b = *(const float4*)&bias[c4];
    s.x = fmaxf(s.x + b.x, 0.f); s.y = fmaxf(s.y + b.y, 0.f);
    s.z = fmaxf(s.z + b.z, 0.f); s.w = fmaxf(s.w + b.w, 0.f);
    ((float4*)X0)[idx4] = s;
}

// ---- merged mask builder: y=0,1 -> threshold masks; y=2 -> An^2 sparse x sparse ----
__global__ __launch_bounds__(256) void maskall_k(const int* __restrict__ cols,
                                                 const float* __restrict__ vals,
                                                 const int* __restrict__ cnt,
                                                 const float* __restrict__ dvec,
                                                 const float* __restrict__ thrp,
                                                 int* __restrict__ mcols,
                                                 float* __restrict__ mvals,
                                                 int* __restrict__ mcnt,
                                                 float* __restrict__ db) {
    __shared__ float ds[NN];
    __shared__ int lcols[MAXR];
    __shared__ float lvals[MAXR];
    __shared__ int lcnt;
    __shared__ float osum;
    int i = blockIdx.x, tid = threadIdx.x, mode = blockIdx.y;
    mcols += (size_t)mode * NN * MAXR;
    mvals += (size_t)mode * NN * MAXR;
    mcnt  += (size_t)mode * NN;
    db    += (size_t)mode * NN;
    int ni = cnt[i], base = i * MAXR;
    float thr = *thrp;
    float di = dvec[i];

    if (mode < 2) {
        if (tid == 0) lcnt = 0;
        __syncthreads();
        float s = 0.f;
        if (tid < ni) {
            int j = cols[base + tid];
            float a = vals[base + tid];
            float m = (mode == 0) ? a : a * di * dvec[j];
            if (m > thr) {
                int p = atomicAdd(&lcnt, 1);
                mcols[base + p] = j;
                mvals[base + p] = a;
                s = a;
            }
        }
        ds[tid] = s; __syncthreads();
        for (int off = 128; off; off >>= 1) {
            if (tid < off) ds[tid] += ds[tid + off];
            __syncthreads();
        }
        if (tid == 0) {
            mcnt[i] = lcnt;
            db[i] = 1.0f / sqrtf(ds[0] + 1.0f);
        }
        return;
    }

    if (tid == 0) { osum = 0.f; lcnt = 0; }
    for (int j = tid; j < NN; j += 256) ds[j] = 0.f;
    __syncthreads();
    for (int t = tid; t < ni; t += 256) {
        int j = cols[base + t];
        float a = vals[base + t];
        lcols[t] = j; lvals[t] = a;
        ds[j] = a * dvec[j] * dvec[j];
    }
    __syncthreads();
    int lane = tid & 63, wv = tid >> 6;
    int sub = lane & 15, dg = lane >> 4;      // 16-lane subgroup, 4 dots/wave in flight
    for (int o = wv * 4 + dg; o < ni; o += 16) {
        int j = lcols[o];
        int nj = cnt[j], bj = j * MAXR;
        float dot = 0.f;
        for (int t = sub; t < nj; t += 16)
            dot += vals[bj + t] * ds[cols[bj + t]];
        #pragma unroll
        for (int off = 8; off; off >>= 1) dot += __shfl_xor(dot, off);
        if (sub == 0 && di * dvec[j] * dot > thr) {
            int p = atomicAdd(&lcnt, 1);
            mcols[base + p] = j;
            mvals[base + p] = lvals[o];
            atomicAdd(&osum, lvals[o]);
        }
    }
    __syncthreads();
    if (tid == 0) {
        mcnt[i] = lcnt;
        db[i] = 1.0f / sqrtf(osum + 1.0f);
    }
}

// ---- branch-batched GEMM: 64x64 tile, 4x4/thread; z = branch; N=128 ----
__global__ __launch_bounds__(256) void gemm3_k(const float* __restrict__ A, int aplane, int lda,
                                               const float* __restrict__ B0,
                                               const float* __restrict__ B1,
                                               const float* __restrict__ B2,
                                               int K, float* __restrict__ out) {
    __shared__ float Ast[16][68];
    __shared__ float Bs[16][64];
    int tid = threadIdx.x;
    int tx = tid & 15, ty = tid >> 4;
    int i0 = blockIdx.x * 64, c0 = blockIdx.y * 64;
    int z = blockIdx.z;
    const float* Ab = A + (size_t)z * aplane;
    const float* B = (z == 0) ? B0 : (z == 1) ? B1 : B2;
    float* outp = out + (size_t)z * NN * 128;
    int sr = tid >> 4, sk = tid & 15;
    int bk = tid >> 4, bc4 = (tid & 15) << 2;

    float ap[4]; float4 bp;
    #pragma unroll
    for (int u = 0; u < 4; u++) ap[u] = Ab[(size_t)(i0 + sr + u * 16) * lda + sk];
    bp = *(const float4*)&B[(size_t)bk * 128 + c0 + bc4];

    float acc[4][4];
    #pragma unroll
    for (int r = 0; r < 4; r++)
        #pragma unroll
        for (int c = 0; c < 4; c++) acc[r][c] = 0.f;

    for (int kt = 0; kt < K; kt += 16) {
        __syncthreads();
        #pragma unroll
        for (int u = 0; u < 4; u++) Ast[sk][sr + u * 16] = ap[u];
        *(float4*)&Bs[bk][bc4] = bp;
        __syncthreads();
        int kn = kt + 16;
        if (kn < K) {
            #pragma unroll
            for (int u = 0; u < 4; u++) ap[u] = Ab[(size_t)(i0 + sr + u * 16) * lda + kn + sk];
            bp = *(const float4*)&B[(size_t)(kn + bk) * 128 + c0 + bc4];
        }
        #pragma unroll
        for (int kk = 0; kk < 16; kk++) {
            float4 a = *(const float4*)&Ast[kk][ty * 4];
            float4 b = *(const float4*)&Bs[kk][tx * 4];
            const float* av = (const float*)&a;
            const float* bv = (const float*)&b;
            #pragma unroll
            for (int r = 0; r < 4; r++)
                #pragma unroll
                for (int c = 0; c < 4; c++) acc[r][c] += av[r] * bv[c];
        }
    }
    #pragma unroll
    for (int r = 0; r < 4; r++) {
        int row = i0 + ty * 4 + r;
        float4 v = make_float4(acc[r][0], acc[r][1], acc[r][2], acc[r][3]);
        *(float4*)&outp[(size_t)row * 128 + c0 + tx * 4] = v;
    }
}

// ---- SpMM: masked CSR, float4 gather, 8-way t-parallel ----
__global__ __launch_bounds__(256) void spmm3_k(const int* __restrict__ mcols,
                                               const float* __restrict__ mvals,
                                               const int* __restrict__ mcnt,
                                               const float* __restrict__ db,
                                               const float* __restrict__ Xin,   // [3][NN][128]
                                               const float* __restrict__ bias0,
                                               const float* __restrict__ bias1,
                                               const float* __restrict__ bias2,
                                               float* __restrict__ outA,        // [3][NN][128] or null
                                               float* __restrict__ embf, int coff) {
    __shared__ float lcoef[MAXR];
    __shared__ int lj[MAXR];
    __shared__ float4 part[8][32];
    int i = blockIdx.x, tid = threadIdx.x, b = blockIdx.y;
    mcols += (size_t)b * NN * MAXR;
    mvals += (size_t)b * NN * MAXR;
    mcnt  += (size_t)b * NN;
    db    += (size_t)b * NN;
    const float* Xb = Xin + (size_t)b * NN * 128;
    const float* bias = (b == 0) ? bias0 : (b == 1) ? bias1 : bias2;
    float dbi = db[i];
    int n = mcnt[i], base = i * MAXR;
    if (tid < n) {
        int j = mcols[base + tid];
        lj[tid] = j;
        lcoef[tid] = mvals[base + tid] * dbi * db[j];
    }
    __syncthreads();
    int g = tid >> 5, c4 = (tid & 31) << 2;
    float4 acc = make_float4(0.f, 0.f, 0.f, 0.f);
    if (g == 0) {
        float4 x = *(const float4*)&Xb[(size_t)i * 128 + c4];
        float d2 = dbi * dbi;
        acc = make_float4(d2 * x.x, d2 * x.y, d2 * x.z, d2 * x.w);
    }
    for (int t = g; t < n; t += 8) {
        float cf = lcoef[t];
        float4 x = *(const float4*)&Xb[(size_t)lj[t] * 128 + c4];
        acc.x += cf * x.x; acc.y += cf * x.y; acc.z += cf * x.z; acc.w += cf * x.w;
    }
    part[g][tid & 31] = acc;
    __syncthreads();
    if (tid < 32) {
        float4 s = part[0][tid];
        #pragma unroll
        for (int gg = 1; gg < 8; gg++) {
            float4 t4 = part[gg][tid];
            s.x += t4.x; s.y += t4.y; s.z += t4.z; s.w += t4.w;
        }
        int cc = tid << 2;
        float4 bv = *(const float4*)&bias[cc];
        s.x = fmaxf(s.x + bv.x, 0.f); s.y = fmaxf(s.y + bv.y, 0.f);
        s.z = fmaxf(s.z + bv.z, 0.f); s.w = fmaxf(s.w + bv.w, 0.f);
        if (outA) *(float4*)&outA[((size_t)b * NN + i) * 128 + cc] = s;
        *(float4*)&embf[((size_t)b * NN + i) * 256 + coff + cc] = s;
    }
}

// ---- dilated 3x3 conv: LDS-staged rows, one block per output row n ----
__global__ __launch_bounds__(256) void conv3f_k(const float* __restrict__ emb,
                                                const float* __restrict__ ck,
                                                const float* __restrict__ cb,
                                                float* __restrict__ outf) {
    __shared__ float rows[3][3][256];
    int n = blockIdx.x, c = threadIdx.x;
    #pragma unroll
    for (int i = 0; i < 3; i++)
        #pragma unroll
        for (int kh = 0; kh < 3; kh++) {
            int nn2 = n + 2 * kh - 2;
            rows[i][kh][c] = (nn2 >= 0 && nn2 < NN) ? emb[((size_t)i * NN + nn2) * 256 + c] : 0.f;
        }
    __syncthreads();
    float s = cb[0];
    #pragma unroll
    for (int i = 0; i < 3; i++)
        #pragma unroll
        for (int kh = 0; kh < 3; kh++)
            #pragma unroll
            for (int kw = 0; kw < 3; kw++) {
                int cc = c + 2 * kw - 2;
                if (cc >= 0 && cc < 256)
                    s += rows[i][kh][cc] * ck[(i * 3 + kh) * 3 + kw];
            }
    outf[(size_t)n * 256 + c] = s;
}

// ---- uv GEMM: uv[node][c] c<64: emb.Wa_left ; c>=64: emb.Wa_right. K-split 2 planes ----
__global__ __launch_bounds__(256) void gemmUV_k(const float* __restrict__ A,   // [NN][256] emb_all
                                                const float* __restrict__ Wa,  // [512][64]
                                                float* __restrict__ uvp) {     // [2][NN][128]
    __shared__ float Ast[16][68];
    __shared__ float Bs[16][64];
    int tid = threadIdx.x;
    int tx = tid & 15, ty = tid >> 4;
    int i0 = blockIdx.x * 64;
    int half = blockIdx.y;
    int z = blockIdx.z;
    int ks = z * 128;
    const float* Bb = Wa + (half ? 256 * 64 : 0);
    int sr = tid >> 4, sk = tid & 15;
    int bk = tid >> 4, bc4 = (tid & 15) << 2;

    float ap[4]; float4 bp;
    #pragma unroll
    for (int u = 0; u < 4; u++) ap[u] = A[(size_t)(i0 + sr + u * 16) * 256 + ks + sk];
    bp = *(const float4*)&Bb[(size_t)(ks + bk) * 64 + bc4];

    float acc[4][4];
    #pragma unroll
    for (int r = 0; r < 4; r++)
        #pragma unroll
        for (int c = 0; c < 4; c++) acc[r][c] = 0.f;

    for (int kt = ks; kt < ks + 128; kt += 16) {
        __syncthreads();
        #pragma unroll
        for (int u = 0; u < 4; u++) Ast[sk][sr + u * 16] = ap[u];
        *(float4*)&Bs[bk][bc4] = bp;
        __syncthreads();
        int kn = kt + 16;
        if (kn < ks + 128) {
            #pragma unroll
            for (int u = 0; u < 4; u++) ap[u] = A[(size_t)(i0 + sr + u * 16) * 256 + kn + sk];
            bp = *(const float4*)&Bb[(size_t)(kn + bk) * 64 + bc4];
        }
        #pragma unroll
        for (int kk = 0; kk < 16; kk++) {
            float4 a = *(const float4*)&Ast[kk][ty * 4];
            float4 b = *(const float4*)&Bs[kk][tx * 4];
            const float* av = (const float*)&a;
            const float* bv = (const float*)&b;
            #pragma unroll
            for (int r = 0; r < 4; r++)
                #pragma unroll
                for (int c = 0; c < 4; c++) acc[r][c] += av[r] * bv[c];
        }
    }
    float* outp = uvp + (size_t)z * NN * 128;
    #pragma unroll
    for (int r = 0; r < 4; r++) {
        int row = i0 + ty * 4 + r;
        float4 v = make_float4(acc[r][0], acc[r][1], acc[r][2], acc[r][3]);
        *(float4*)&outp[(size_t)row * 128 + half * 64 + tx * 4] = v;
    }
}

// ---- pair gather + logits: 16 pairs/block, 4 per wave ----
__global__ __launch_bounds__(256) void pairuv_k(const int* __restrict__ left,
                                                const int* __restrict__ right,
                                                const float* __restrict__ uvp,
                                                const float* __restrict__ ba,
                                                const float* __restrict__ Wb,
                                                const float* __restrict__ bb,
                                                float* __restrict__ out) {
    int tid = threadIdx.x;
    int w = tid >> 6, c = tid & 63;
    int base = blockIdx.x * 16 + w * 4;
    const float* u0 = uvp;
    const float* u1 = uvp + (size_t)NN * 128;
    float bac = ba[c];
    float w0 = Wb[c * 2], w1 = Wb[c * 2 + 1];
    float b0 = bb[0], b1 = bb[1];
    #pragma unroll
    for (int pp = 0; pp < 4; pp++) {
        int row = base + pp;
        int l = left[row], r = right[row];
        float h = u0[(size_t)l * 128 + c] + u1[(size_t)l * 128 + c]
                + u0[(size_t)r * 128 + 64 + c] + u1[(size_t)r * 128 + 64 + c] + bac;
        h = fmaxf(h, 0.f);
        float s0 = h * w0, s1 = h * w1;
        for (int off = 32; off; off >>= 1) {
            s0 += __shfl_xor(s0, off);
            s1 += __shfl_xor(s1, off);
        }
        if (c == 0) {
            out[row * 2]     = s0 + b0;
            out[row * 2 + 1] = s1 + b1;
        }
    }
}

extern "C" void kernel_launch(void* const* d_in, const int* in_sizes, int n_in,
                              void* d_out, int out_size, void* d_ws, size_t ws_size,
                              hipStream_t stream) {
    const int* left  = (const int*)d_in[0];
    const int* right = (const int*)d_in[1];
    const float* X    = (const float*)d_in[2];
    const float* adj  = (const float*)d_in[3];
    const float* thr  = (const float*)d_in[4];
    const float* Wfc1 = (const float*)d_in[5];
    const float* bfc1 = (const float*)d_in[6];
    // channel order b0,b1,b2 = (adj mask, Wg5/6), (An mask, Wg3/4), (An^2 mask, Wg1/2)
    const float* Wga[3] = { (const float*)d_in[15], (const float*)d_in[11], (const float*)d_in[7] };
    const float* bga[3] = { (const float*)d_in[16], (const float*)d_in[12], (const float*)d_in[8] };
    const float* Wgb[3] = { (const float*)d_in[17], (const float*)d_in[13], (const float*)d_in[9] };
    const float* bgb[3] = { (const float*)d_in[18], (const float*)d_in[14], (const float*)d_in[10] };
    const float* cnnk = (const float*)d_in[19];
    const float* cnnb = (const float*)d_in[20];
    const float* Wa_  = (const float*)d_in[21];
    const float* ba_  = (const float*)d_in[22];
    const float* Wb_  = (const float*)d_in[23];
    const float* bb_  = (const float*)d_in[24];

    char* p = (char*)d_ws;
    auto take = [&](size_t n) { char* q = p; p += (n + 255) & ~(size_t)255; return q; };
    float* dvec = (float*)take(NN * 4);
    float* db3  = (float*)take((size_t)3 * NN * 4);
    int*   cnt  = (int*)take(NN * 4);
    int*   mcnt3 = (int*)take((size_t)3 * NN * 4);
    int*   cols = (int*)take((size_t)NN * MAXR * 4);
    float* vals = (float*)take((size_t)NN * MAXR * 4);
    int*   mcols3 = (int*)take((size_t)3 * NN * MAXR * 4);    // 7.1 MB (contiguous with mvals3)
    float* mvals3 = (float*)take((size_t)3 * NN * MAXR * 4);  // 7.1 MB
    float* X0    = (float*)take((size_t)NN * 256 * 4);
    float* XWall = (float*)take((size_t)3 * NN * 128 * 4);
    float* e1all = (float*)take((size_t)3 * NN * 128 * 4);
    float* HW2all= (float*)take((size_t)3 * NN * 128 * 4);
    float* embf  = (float*)take((size_t)3 * NN * 256 * 4);
    __bf16* Xl   = (__bf16*)take((size_t)NN * KP * 2);        // 9.6 MB
    __bf16* WhT  = (__bf16*)take((size_t)256 * KP * 2);       // 0.8 MB
    __bf16* WlT  = (__bf16*)take((size_t)256 * KP * 2);       // 0.8 MB
    // Xh (9.6 MB) aliases mcols3+mvals3 (14.2 MB contiguous): dead once fc1m completes,
    // before maskall_k writes mcols3/mvals3.
    __bf16* Xh = (__bf16*)mcols3;
    // Cpart: KSPLIT(=7) planes of NN*256 f32 = 22.0 MB aliasing XWall..embf (23.6 MB);
    // consumed by reduce7_k before XWall/e1all/HW2all/embf are written.
    float* Cpart = XWall;
    // uvp: 2 planes of NN*128 f32 = 3.1 MB aliasing embf (dead after conv3f_k).
    float* uvp = embf;

    float* out_logits = (float*)d_out;
    float* out_emb = out_logits + 32768;

    // fused prep: xsplit + wsplit + csr build
    prep_k<<<XSPLIT_BLOCKS + WSPLIT_BLOCKS + CSR_BLOCKS, 256, 0, stream>>>(
        adj, cols, vals, cnt, dvec, X, Xh, Xl, Wfc1, WhT, WlT);

    // fc1: X0 = relu(X @ Wfc1 + b), MFMA split-K + reduce
    fc1m_k<<<dim3(NN / 64, 4, KSPLIT), 256, 0, stream>>>(Xh, Xl, WhT, WlT, Cpart);
    reduce7_k<<<NN * 64 / 256, 256, 0, stream>>>(Cpart, bfc1, X0);

    // all three branch masks in one dispatch (y=0,1 light; y=2 heavy M2)
    maskall_k<<<dim3(NN, 3), 256, 0, stream>>>(cols, vals, cnt, dvec, thr,
                                               mcols3, mvals3, mcnt3, db3);

    // XW[b] = X0 @ Wga[b]
    gemm3_k<<<dim3(NN / 64, 2, 3), 256, 0, stream>>>(X0, 0, 256, Wga[0], Wga[1], Wga[2], 256, XWall);
    // e1[b] = relu(An_b @ XW[b] + bga[b]) -> e1all + embf cols 0..127
    spmm3_k<<<dim3(NN, 3), 256, 0, stream>>>(mcols3, mvals3, mcnt3, db3, XWall,
                                             bga[0], bga[1], bga[2], e1all, embf, 0);
    // HW2[b] = e1[b] @ Wgb[b]
    gemm3_k<<<dim3(NN / 64, 2, 3), 256, 0, stream>>>(e1all, NN * 128, 128, Wgb[0], Wgb[1], Wgb[2], 128, HW2all);
    // e2[b] = relu(An_b @ HW2[b] + bgb[b]) -> embf cols 128..255
    spmm3_k<<<dim3(NN, 3), 256, 0, stream>>>(mcols3, mvals3, mcnt3, db3, HW2all,
                                             bgb[0], bgb[1], bgb[2], (float*)0, embf, 128);

    conv3f_k<<<NN, 256, 0, stream>>>(embf, cnnk, cnnb, out_emb);
    // pair MLP via u/v decomposition: uv = emb_all @ [Wa_left | Wa_right]
    gemmUV_k<<<dim3(NN / 64, 2, 2), 256, 0, stream>>>(out_emb, Wa_, uvp);
    pairuv_k<<<16384 / 16, 256, 0, stream>>>(left, right, uvp, ba_, Wb_, bb_, out_logits);
}

// Round 22
// 306.730 us; speedup vs baseline: 1.3000x; 1.0519x over previous
//
#include <hip/hip_runtime.h>

#define NN 3072
#define FIN 1546
#define KP 1568          // FIN padded to multiple of 32
#define MAXR 192         // max CSR nnz/row (measured mean ~61)
#define KSPLIT 7
#define KSLICE 224       // 7*224 = 1568

#define XS4_BLOCKS (NN * KP / 1024)        // 4704  (4 elems/thread)
#define WSPLIT_BLOCKS (256 * KP / 256)     // 1568
#define CSR_BLOCKS (NN / 4)                // 768

typedef __attribute__((ext_vector_type(8))) __bf16 bf16x8;
typedef __attribute__((ext_vector_type(4))) __bf16 bf16x4;
typedef __attribute__((ext_vector_type(4))) float f32x4;

// ---- fused prep v2: [0,XS4) xsplit x4 ; [XS4,+WS) wsplit ; rest csr (float4+ballot4) ----
__global__ __launch_bounds__(256) void prep_k(const float* __restrict__ adj,
                                              int* __restrict__ cols, float* __restrict__ vals,
                                              int* __restrict__ cnt, float* __restrict__ dvec,
                                              const float* __restrict__ X,
                                              __bf16* __restrict__ Xh, __bf16* __restrict__ Xl,
                                              const float* __restrict__ W,
                                              __bf16* __restrict__ WhT, __bf16* __restrict__ WlT) {
    int bid = blockIdx.x;
    if (bid < XS4_BLOCKS) {
        int e = (bid * 256 + threadIdx.x) * 4;        // 4 elems, same row (KP%4==0)
        int i = e / KP, c = e - i * KP;
        const float* xr = X + (size_t)i * FIN + c;
        float x0 = (c + 0 < FIN) ? xr[0] : 0.f;
        float x1 = (c + 1 < FIN) ? xr[1] : 0.f;
        float x2 = (c + 2 < FIN) ? xr[2] : 0.f;
        float x3 = (c + 3 < FIN) ? xr[3] : 0.f;
        __bf16 h0 = (__bf16)x0, h1 = (__bf16)x1, h2 = (__bf16)x2, h3 = (__bf16)x3;
        bf16x4 hv = {h0, h1, h2, h3};
        bf16x4 lv = {(__bf16)(x0 - (float)h0), (__bf16)(x1 - (float)h1),
                     (__bf16)(x2 - (float)h2), (__bf16)(x3 - (float)h3)};
        *(bf16x4*)(Xh + e) = hv;
        *(bf16x4*)(Xl + e) = lv;
        return;
    }
    bid -= XS4_BLOCKS;
    if (bid < WSPLIT_BLOCKS) {
        int idx = bid * 256 + threadIdx.x;
        int c = idx / KP, k = idx - c * KP;
        float x = (k < FIN) ? W[(size_t)k * 256 + c] : 0.f;
        __bf16 h = (__bf16)x;
        WhT[idx] = h;
        WlT[idx] = (__bf16)(x - (float)h);
        return;
    }
    bid -= WSPLIT_BLOCKS;
    int i = bid * 4 + (threadIdx.x >> 6);
    int lane = threadIdx.x & 63;
    const float* row = adj + (size_t)i * NN;
    unsigned long long below = (1ull << lane) - 1ull;
    float s = 0.f; int count = 0;
    int base = i * MAXR;
    for (int c0 = 0; c0 < NN; c0 += 256) {
        float4 a4 = *(const float4*)(row + c0 + lane * 4);
        float a[4] = {a4.x, a4.y, a4.z, a4.w};
        s += a[0] + a[1] + a[2] + a[3];
        unsigned long long bal[4];
        #pragma unroll
        for (int u = 0; u < 4; u++) bal[u] = __ballot(a[u] != 0.f);
        int before = 0;
        #pragma unroll
        for (int u = 0; u < 4; u++) before += __popcll(bal[u] & below);
        int local = 0;
        #pragma unroll
        for (int u = 0; u < 4; u++) {
            if (a[u] != 0.f) {
                int pos = count + before + local;
                if (pos < MAXR) { cols[base + pos] = c0 + lane * 4 + u; vals[base + pos] = a[u]; }
                local++;
            }
        }
        int tot = 0;
        #pragma unroll
        for (int u = 0; u < 4; u++) tot += __popcll(bal[u]);
        count += tot;
    }
    for (int off = 32; off; off >>= 1) s += __shfl_xor(s, off);
    if (lane == 0) {
        cnt[i] = count < MAXR ? count : MAXR;
        dvec[i] = (s > 0.f) ? 1.0f / sqrtf(s) : 0.f;
    }
}

// ---- fc1 MFMA: 64x64 tile, 4 waves, split-K (R19-measured config) ----
__global__ __launch_bounds__(256) void fc1m_k(const __bf16* __restrict__ Xh,
                                              const __bf16* __restrict__ Xl,
                                              const __bf16* __restrict__ WhT,
                                              const __bf16* __restrict__ WlT,
                                              float* __restrict__ Cpart) {
    int tid = threadIdx.x;
    int w = tid >> 6, lane = tid & 63;
    int m = lane & 15, q = lane >> 4;
    int i0 = blockIdx.x * 64, c0 = blockIdx.y * 64;
    int z = blockIdx.z;
    int k0 = z * KSLICE;
    int rowA = i0 + w * 16 + m;
    const __bf16* xh = Xh + (size_t)rowA * KP + k0 + q * 8;
    const __bf16* xl = Xl + (size_t)rowA * KP + k0 + q * 8;
    const __bf16* bh0 = WhT + (size_t)(c0 + m) * KP + k0 + q * 8;
    const __bf16* bl0 = WlT + (size_t)(c0 + m) * KP + k0 + q * 8;

    f32x4 acc[4];
    #pragma unroll
    for (int ct = 0; ct < 4; ct++)
        #pragma unroll
        for (int r = 0; r < 4; r++) acc[ct][r] = 0.f;

    for (int ks = 0; ks < KSLICE; ks += 32) {
        bf16x8 ah = *(const bf16x8*)(xh + ks);
        bf16x8 al = *(const bf16x8*)(xl + ks);
        #pragma unroll
        for (int ct = 0; ct < 4; ct++) {
            bf16x8 bh = *(const bf16x8*)(bh0 + (size_t)ct * 16 * KP + ks);
            bf16x8 bl = *(const bf16x8*)(bl0 + (size_t)ct * 16 * KP + ks);
            acc[ct] = __builtin_amdgcn_mfma_f32_16x16x32_bf16(ah, bh, acc[ct], 0, 0, 0);
            acc[ct] = __builtin_amdgcn_mfma_f32_16x16x32_bf16(ah, bl, acc[ct], 0, 0, 0);
            acc[ct] = __builtin_amdgcn_mfma_f32_16x16x32_bf16(al, bh, acc[ct], 0, 0, 0);
        }
    }
    float* outp = Cpart + (size_t)z * NN * 256;
    int rowBase = i0 + w * 16 + q * 4;
    #pragma unroll
    for (int ct = 0; ct < 4; ct++) {
        int col = c0 + ct * 16 + m;
        #pragma unroll
        for (int r = 0; r < 4; r++)
            outp[(size_t)(rowBase + r) * 256 + col] = acc[ct][r];
    }
}

// ---- fc1 stage 2: reduce KSPLIT partials + bias + relu (float4) ----
__global__ void reduce7_k(const float* __restrict__ Cpart, const float* __restrict__ bias,
                          float* __restrict__ X0) {
    int idx4 = blockIdx.x * 256 + threadIdx.x;
    int c4 = (idx4 & 63) << 2;
    float4 s = ((const float4*)Cpart)[idx4];
    #pragma unroll
    for (int z = 1; z < KSPLIT; z++) {
        float4 t = ((const float4*)(Cpart + (size_t)z * NN * 256))[idx4];
        s.x += t.x; s.y += t.y; s.z += t.z; s.w += t.w;
    }
    float4 b = *(const float4*)&bias[c4];
    s.x = fmaxf(s.x + b.x, 0.f); s.y = fmaxf(s.y + b.y, 0.f);
    s.z = fmaxf(s.z + b.z, 0.f); s.w = fmaxf(s.w + b.w, 0.f);
    ((float4*)X0)[idx4] = s;
}

// ---- merged mask builder: y=0,1 -> threshold masks; y=2 -> An^2 sparse x sparse ----
__global__ __launch_bounds__(256) void maskall_k(const int* __restrict__ cols,
                                                 const float* __restrict__ vals,
                                                 const int* __restrict__ cnt,
                                                 const float* __restrict__ dvec,
                                                 const float* __restrict__ thrp,
                                                 int* __restrict__ mcols,
                                                 float* __restrict__ mvals,
                                                 int* __restrict__ mcnt,
                                                 float* __restrict__ db) {
    __shared__ float ds[NN];
    __shared__ int lcols[MAXR];
    __shared__ float lvals[MAXR];
    __shared__ int lcnt;
    __shared__ float osum;
    int i = blockIdx.x, tid = threadIdx.x, mode = blockIdx.y;
    mcols += (size_t)mode * NN * MAXR;
    mvals += (size_t)mode * NN * MAXR;
    mcnt  += (size_t)mode * NN;
    db    += (size_t)mode * NN;
    int ni = cnt[i], base = i * MAXR;
    float thr = *thrp;
    float di = dvec[i];

    if (mode < 2) {
        if (tid == 0) lcnt = 0;
        __syncthreads();
        float s = 0.f;
        if (tid < ni) {
            int j = cols[base + tid];
            float a = vals[base + tid];
            float m = (mode == 0) ? a : a * di * dvec[j];
            if (m > thr) {
                int p = atomicAdd(&lcnt, 1);
                mcols[base + p] = j;
                mvals[base + p] = a;
                s = a;
            }
        }
        ds[tid] = s; __syncthreads();
        for (int off = 128; off; off >>= 1) {
            if (tid < off) ds[tid] += ds[tid + off];
            __syncthreads();
        }
        if (tid == 0) {
            mcnt[i] = lcnt;
            db[i] = 1.0f / sqrtf(ds[0] + 1.0f);
        }
        return;
    }

    if (tid == 0) { osum = 0.f; lcnt = 0; }
    for (int j = tid; j < NN; j += 256) ds[j] = 0.f;
    __syncthreads();
    for (int t = tid; t < ni; t += 256) {
        int j = cols[base + t];
        float a = vals[base + t];
        lcols[t] = j; lvals[t] = a;
        ds[j] = a * dvec[j] * dvec[j];
    }
    __syncthreads();
    int lane = tid & 63, wv = tid >> 6;
    int sub = lane & 15, dg = lane >> 4;      // 16-lane subgroup, 4 dots/wave in flight
    for (int o = wv * 4 + dg; o < ni; o += 16) {
        int j = lcols[o];
        int nj = cnt[j], bj = j * MAXR;
        float dot = 0.f;
        for (int t = sub; t < nj; t += 16)
            dot += vals[bj + t] * ds[cols[bj + t]];
        #pragma unroll
        for (int off = 8; off; off >>= 1) dot += __shfl_xor(dot, off);
        if (sub == 0 && di * dvec[j] * dot > thr) {
            int p = atomicAdd(&lcnt, 1);
            mcols[base + p] = j;
            mvals[base + p] = lvals[o];
            atomicAdd(&osum, lvals[o]);
        }
    }
    __syncthreads();
    if (tid == 0) {
        mcnt[i] = lcnt;
        db[i] = 1.0f / sqrtf(osum + 1.0f);
    }
}

// ---- branch-batched GEMM: 64x64 tile, 4x4/thread; z = branch; N=128 ----
__global__ __launch_bounds__(256) void gemm3_k(const float* __restrict__ A, int aplane, int lda,
                                               const float* __restrict__ B0,
                                               const float* __restrict__ B1,
                                               const float* __restrict__ B2,
                                               int K, float* __restrict__ out) {
    __shared__ float Ast[16][68];
    __shared__ float Bs[16][64];
    int tid = threadIdx.x;
    int tx = tid & 15, ty = tid >> 4;
    int i0 = blockIdx.x * 64, c0 = blockIdx.y * 64;
    int z = blockIdx.z;
    const float* Ab = A + (size_t)z * aplane;
    const float* B = (z == 0) ? B0 : (z == 1) ? B1 : B2;
    float* outp = out + (size_t)z * NN * 128;
    int sr = tid >> 4, sk = tid & 15;
    int bk = tid >> 4, bc4 = (tid & 15) << 2;

    float ap[4]; float4 bp;
    #pragma unroll
    for (int u = 0; u < 4; u++) ap[u] = Ab[(size_t)(i0 + sr + u * 16) * lda + sk];
    bp = *(const float4*)&B[(size_t)bk * 128 + c0 + bc4];

    float acc[4][4];
    #pragma unroll
    for (int r = 0; r < 4; r++)
        #pragma unroll
        for (int c = 0; c < 4; c++) acc[r][c] = 0.f;

    for (int kt = 0; kt < K; kt += 16) {
        __syncthreads();
        #pragma unroll
        for (int u = 0; u < 4; u++) Ast[sk][sr + u * 16] = ap[u];
        *(float4*)&Bs[bk][bc4] = bp;
        __syncthreads();
        int kn = kt + 16;
        if (kn < K) {
            #pragma unroll
            for (int u = 0; u < 4; u++) ap[u] = Ab[(size_t)(i0 + sr + u * 16) * lda + kn + sk];
            bp = *(const float4*)&B[(size_t)(kn + bk) * 128 + c0 + bc4];
        }
        #pragma unroll
        for (int kk = 0; kk < 16; kk++) {
            float4 a = *(const float4*)&Ast[kk][ty * 4];
            float4 b = *(const float4*)&Bs[kk][tx * 4];
            const float* av = (const float*)&a;
            const float* bv = (const float*)&b;
            #pragma unroll
            for (int r = 0; r < 4; r++)
                #pragma unroll
                for (int c = 0; c < 4; c++) acc[r][c] += av[r] * bv[c];
        }
    }
    #pragma unroll
    for (int r = 0; r < 4; r++) {
        int row = i0 + ty * 4 + r;
        float4 v = make_float4(acc[r][0], acc[r][1], acc[r][2], acc[r][3]);
        *(float4*)&outp[(size_t)row * 128 + c0 + tx * 4] = v;
    }
}

// ---- SpMM: masked CSR, float4 gather, 8-way t-parallel ----
__global__ __launch_bounds__(256) void spmm3_k(const int* __restrict__ mcols,
                                               const float* __restrict__ mvals,
                                               const int* __restrict__ mcnt,
                                               const float* __restrict__ db,
                                               const float* __restrict__ Xin,   // [3][NN][128]
                                               const float* __restrict__ bias0,
                                               const float* __restrict__ bias1,
                                               const float* __restrict__ bias2,
                                               float* __restrict__ outA,        // [3][NN][128] or null
                                               float* __restrict__ embf, int coff) {
    __shared__ float lcoef[MAXR];
    __shared__ int lj[MAXR];
    __shared__ float4 part[8][32];
    int i = blockIdx.x, tid = threadIdx.x, b = blockIdx.y;
    mcols += (size_t)b * NN * MAXR;
    mvals += (size_t)b * NN * MAXR;
    mcnt  += (size_t)b * NN;
    db    += (size_t)b * NN;
    const float* Xb = Xin + (size_t)b * NN * 128;
    const float* bias = (b == 0) ? bias0 : (b == 1) ? bias1 : bias2;
    float dbi = db[i];
    int n = mcnt[i], base = i * MAXR;
    if (tid < n) {
        int j = mcols[base + tid];
        lj[tid] = j;
        lcoef[tid] = mvals[base + tid] * dbi * db[j];
    }
    __syncthreads();
    int g = tid >> 5, c4 = (tid & 31) << 2;
    float4 acc = make_float4(0.f, 0.f, 0.f, 0.f);
    if (g == 0) {
        float4 x = *(const float4*)&Xb[(size_t)i * 128 + c4];
        float d2 = dbi * dbi;
        acc = make_float4(d2 * x.x, d2 * x.y, d2 * x.z, d2 * x.w);
    }
    for (int t = g; t < n; t += 8) {
        float cf = lcoef[t];
        float4 x = *(const float4*)&Xb[(size_t)lj[t] * 128 + c4];
        acc.x += cf * x.x; acc.y += cf * x.y; acc.z += cf * x.z; acc.w += cf * x.w;
    }
    part[g][tid & 31] = acc;
    __syncthreads();
    if (tid < 32) {
        float4 s = part[0][tid];
        #pragma unroll
        for (int gg = 1; gg < 8; gg++) {
            float4 t4 = part[gg][tid];
            s.x += t4.x; s.y += t4.y; s.z += t4.z; s.w += t4.w;
        }
        int cc = tid << 2;
        float4 bv = *(const float4*)&bias[cc];
        s.x = fmaxf(s.x + bv.x, 0.f); s.y = fmaxf(s.y + bv.y, 0.f);
        s.z = fmaxf(s.z + bv.z, 0.f); s.w = fmaxf(s.w + bv.w, 0.f);
        if (outA) *(float4*)&outA[((size_t)b * NN + i) * 128 + cc] = s;
        *(float4*)&embf[((size_t)b * NN + i) * 256 + coff + cc] = s;
    }
}

// ---- dilated 3x3 conv: LDS-staged rows, one block per output row n ----
__global__ __launch_bounds__(256) void conv3f_k(const float* __restrict__ emb,
                                                const float* __restrict__ ck,
                                                const float* __restrict__ cb,
                                                float* __restrict__ outf) {
    __shared__ float rows[3][3][256];
    int n = blockIdx.x, c = threadIdx.x;
    #pragma unroll
    for (int i = 0; i < 3; i++)
        #pragma unroll
        for (int kh = 0; kh < 3; kh++) {
            int nn2 = n + 2 * kh - 2;
            rows[i][kh][c] = (nn2 >= 0 && nn2 < NN) ? emb[((size_t)i * NN + nn2) * 256 + c] : 0.f;
        }
    __syncthreads();
    float s = cb[0];
    #pragma unroll
    for (int i = 0; i < 3; i++)
        #pragma unroll
        for (int kh = 0; kh < 3; kh++)
            #pragma unroll
            for (int kw = 0; kw < 3; kw++) {
                int cc = c + 2 * kw - 2;
                if (cc >= 0 && cc < 256)
                    s += rows[i][kh][cc] * ck[(i * 3 + kh) * 3 + kw];
            }
    outf[(size_t)n * 256 + c] = s;
}

// ---- uv GEMM: uv[node][c] c<64: emb.Wa_left ; c>=64: emb.Wa_right. K-split 2 planes ----
__global__ __launch_bounds__(256) void gemmUV_k(const float* __restrict__ A,   // [NN][256] emb_all
                                                const float* __restrict__ Wa,  // [512][64]
                                                float* __restrict__ uvp) {     // [2][NN][128]
    __shared__ float Ast[16][68];
    __shared__ float Bs[16][64];
    int tid = threadIdx.x;
    int tx = tid & 15, ty = tid >> 4;
    int i0 = blockIdx.x * 64;
    int half = blockIdx.y;
    int z = blockIdx.z;
    int ks = z * 128;
    const float* Bb = Wa + (half ? 256 * 64 : 0);
    int sr = tid >> 4, sk = tid & 15;
    int bk = tid >> 4, bc4 = (tid & 15) << 2;

    float ap[4]; float4 bp;
    #pragma unroll
    for (int u = 0; u < 4; u++) ap[u] = A[(size_t)(i0 + sr + u * 16) * 256 + ks + sk];
    bp = *(const float4*)&Bb[(size_t)(ks + bk) * 64 + bc4];

    float acc[4][4];
    #pragma unroll
    for (int r = 0; r < 4; r++)
        #pragma unroll
        for (int c = 0; c < 4; c++) acc[r][c] = 0.f;

    for (int kt = ks; kt < ks + 128; kt += 16) {
        __syncthreads();
        #pragma unroll
        for (int u = 0; u < 4; u++) Ast[sk][sr + u * 16] = ap[u];
        *(float4*)&Bs[bk][bc4] = bp;
        __syncthreads();
        int kn = kt + 16;
        if (kn < ks + 128) {
            #pragma unroll
            for (int u = 0; u < 4; u++) ap[u] = A[(size_t)(i0 + sr + u * 16) * 256 + kn + sk];
            bp = *(const float4*)&Bb[(size_t)(kn + bk) * 64 + bc4];
        }
        #pragma unroll
        for (int kk = 0; kk < 16; kk++) {
            float4 a = *(const float4*)&Ast[kk][ty * 4];
            float4 b = *(const float4*)&Bs[kk][tx * 4];
            const float* av = (const float*)&a;
            const float* bv = (const float*)&b;
            #pragma unroll
            for (int r = 0; r < 4; r++)
                #pragma unroll
                for (int c = 0; c < 4; c++) acc[r][c] += av[r] * bv[c];
        }
    }
    float* outp = uvp + (size_t)z * NN * 128;
    #pragma unroll
    for (int r = 0; r < 4; r++) {
        int row = i0 + ty * 4 + r;
        float4 v = make_float4(acc[r][0], acc[r][1], acc[r][2], acc[r][3]);
        *(float4*)&outp[(size_t)row * 128 + half * 64 + tx * 4] = v;
    }
}

// ---- pair gather + logits: 16 pairs/block, 4 per wave ----
__global__ __launch_bounds__(256) void pairuv_k(const int* __restrict__ left,
                                                const int* __restrict__ right,
                                                const float* __restrict__ uvp,
                                                const float* __restrict__ ba,
                                                const float* __restrict__ Wb,
                                                const float* __restrict__ bb,
                                                float* __restrict__ out) {
    int tid = threadIdx.x;
    int w = tid >> 6, c = tid & 63;
    int base = blockIdx.x * 16 + w * 4;
    const float* u0 = uvp;
    const float* u1 = uvp + (size_t)NN * 128;
    float bac = ba[c];
    float w0 = Wb[c * 2], w1 = Wb[c * 2 + 1];
    float b0 = bb[0], b1 = bb[1];
    #pragma unroll
    for (int pp = 0; pp < 4; pp++) {
        int row = base + pp;
        int l = left[row], r = right[row];
        float h = u0[(size_t)l * 128 + c] + u1[(size_t)l * 128 + c]
                + u0[(size_t)r * 128 + 64 + c] + u1[(size_t)r * 128 + 64 + c] + bac;
        h = fmaxf(h, 0.f);
        float s0 = h * w0, s1 = h * w1;
        for (int off = 32; off; off >>= 1) {
            s0 += __shfl_xor(s0, off);
            s1 += __shfl_xor(s1, off);
        }
        if (c == 0) {
            out[row * 2]     = s0 + b0;
            out[row * 2 + 1] = s1 + b1;
        }
    }
}

extern "C" void kernel_launch(void* const* d_in, const int* in_sizes, int n_in,
                              void* d_out, int out_size, void* d_ws, size_t ws_size,
                              hipStream_t stream) {
    const int* left  = (const int*)d_in[0];
    const int* right = (const int*)d_in[1];
    const float* X    = (const float*)d_in[2];
    const float* adj  = (const float*)d_in[3];
    const float* thr  = (const float*)d_in[4];
    const float* Wfc1 = (const float*)d_in[5];
    const float* bfc1 = (const float*)d_in[6];
    // channel order b0,b1,b2 = (adj mask, Wg5/6), (An mask, Wg3/4), (An^2 mask, Wg1/2)
    const float* Wga[3] = { (const float*)d_in[15], (const float*)d_in[11], (const float*)d_in[7] };
    const float* bga[3] = { (const float*)d_in[16], (const float*)d_in[12], (const float*)d_in[8] };
    const float* Wgb[3] = { (const float*)d_in[17], (const float*)d_in[13], (const float*)d_in[9] };
    const float* bgb[3] = { (const float*)d_in[18], (const float*)d_in[14], (const float*)d_in[10] };
    const float* cnnk = (const float*)d_in[19];
    const float* cnnb = (const float*)d_in[20];
    const float* Wa_  = (const float*)d_in[21];
    const float* ba_  = (const float*)d_in[22];
    const float* Wb_  = (const float*)d_in[23];
    const float* bb_  = (const float*)d_in[24];

    char* p = (char*)d_ws;
    auto take = [&](size_t n) { char* q = p; p += (n + 255) & ~(size_t)255; return q; };
    float* dvec = (float*)take(NN * 4);
    float* db3  = (float*)take((size_t)3 * NN * 4);
    int*   cnt  = (int*)take(NN * 4);
    int*   mcnt3 = (int*)take((size_t)3 * NN * 4);
    int*   cols = (int*)take((size_t)NN * MAXR * 4);
    float* vals = (float*)take((size_t)NN * MAXR * 4);
    int*   mcols3 = (int*)take((size_t)3 * NN * MAXR * 4);    // 7.1 MB (contiguous with mvals3)
    float* mvals3 = (float*)take((size_t)3 * NN * MAXR * 4);  // 7.1 MB
    float* X0    = (float*)take((size_t)NN * 256 * 4);
    float* XWall = (float*)take((size_t)3 * NN * 128 * 4);
    float* e1all = (float*)take((size_t)3 * NN * 128 * 4);
    float* HW2all= (float*)take((size_t)3 * NN * 128 * 4);
    float* embf  = (float*)take((size_t)3 * NN * 256 * 4);
    __bf16* Xl   = (__bf16*)take((size_t)NN * KP * 2);        // 9.6 MB
    __bf16* WhT  = (__bf16*)take((size_t)256 * KP * 2);       // 0.8 MB
    __bf16* WlT  = (__bf16*)take((size_t)256 * KP * 2);       // 0.8 MB
    // Xh (9.6 MB) aliases mcols3+mvals3 (14.2 MB contiguous): dead once fc1m completes,
    // before maskall_k writes mcols3/mvals3.
    __bf16* Xh = (__bf16*)mcols3;
    // Cpart: KSPLIT(=7) planes of NN*256 f32 = 22.0 MB aliasing XWall..embf (23.6 MB);
    // consumed by reduce7_k before XWall/e1all/HW2all/embf are written.
    float* Cpart = XWall;
    // uvp: 2 planes of NN*128 f32 = 3.1 MB aliasing embf (dead after conv3f_k).
    float* uvp = embf;

    float* out_logits = (float*)d_out;
    float* out_emb = out_logits + 32768;

    // fused prep: xsplit (x4 ILP) + wsplit + csr build (float4 + ballot4)
    prep_k<<<XS4_BLOCKS + WSPLIT_BLOCKS + CSR_BLOCKS, 256, 0, stream>>>(
        adj, cols, vals, cnt, dvec, X, Xh, Xl, Wfc1, WhT, WlT);

    // fc1: X0 = relu(X @ Wfc1 + b), MFMA split-K + reduce
    fc1m_k<<<dim3(NN / 64, 4, KSPLIT), 256, 0, stream>>>(Xh, Xl, WhT, WlT, Cpart);
    reduce7_k<<<NN * 64 / 256, 256, 0, stream>>>(Cpart, bfc1, X0);

    // all three branch masks in one dispatch (y=0,1 light; y=2 heavy M2)
    maskall_k<<<dim3(NN, 3), 256, 0, stream>>>(cols, vals, cnt, dvec, thr,
                                               mcols3, mvals3, mcnt3, db3);

    // XW[b] = X0 @ Wga[b]
    gemm3_k<<<dim3(NN / 64, 2, 3), 256, 0, stream>>>(X0, 0, 256, Wga[0], Wga[1], Wga[2], 256, XWall);
    // e1[b] = relu(An_b @ XW[b] + bga[b]) -> e1all + embf cols 0..127
    spmm3_k<<<dim3(NN, 3), 256, 0, stream>>>(mcols3, mvals3, mcnt3, db3, XWall,
                                             bga[0], bga[1], bga[2], e1all, embf, 0);
    // HW2[b] = e1[b] @ Wgb[b]
    gemm3_k<<<dim3(NN / 64, 2, 3), 256, 0, stream>>>(e1all, NN * 128, 128, Wgb[0], Wgb[1], Wgb[2], 128, HW2all);
    // e2[b] = relu(An_b @ HW2[b] + bgb[b]) -> embf cols 128..255
    spmm3_k<<<dim3(NN, 3), 256, 0, stream>>>(mcols3, mvals3, mcnt3, db3, HW2all,
                                             bgb[0], bgb[1], bgb[2], (float*)0, embf, 128);

    conv3f_k<<<NN, 256, 0, stream>>>(embf, cnnk, cnnb, out_emb);
    // pair MLP via u/v decomposition: uv = emb_all @ [Wa_left | Wa_right]
    gemmUV_k<<<dim3(NN / 64, 2, 2), 256, 0, stream>>>(out_emb, Wa_, uvp);
    pairuv_k<<<16384 / 16, 256, 0, stream>>>(left, right, uvp, ba_, Wb_, bb_, out_logits);
}

// Round 23
// 304.480 us; speedup vs baseline: 1.3096x; 1.0074x over previous
//
#include <hip/hip_runtime.h>

#define NN 3072
#define FIN 1546
#define KP 1568          // FIN padded to multiple of 32
#define MAXR 192         // max CSR nnz/row (measured mean ~61)
#define KSPLIT 7
#define KSLICE 224       // 7*224 = 1568

#define XS4_BLOCKS (NN * KP / 1024)        // 4704  (4 elems/thread)
#define WSPLIT_BLOCKS (256 * KP / 256)     // 1568
#define CSR_BLOCKS (NN / 4)                // 768

typedef __attribute__((ext_vector_type(8))) __bf16 bf16x8;
typedef __attribute__((ext_vector_type(4))) __bf16 bf16x4;
typedef __attribute__((ext_vector_type(4))) float f32x4;

// ---- fused prep: [0,XS4) xsplit x4 ; [XS4,+WS) wsplit ; rest csr (float4+ballot4) ----
__global__ __launch_bounds__(256) void prep_k(const float* __restrict__ adj,
                                              int* __restrict__ cols, float* __restrict__ vals,
                                              int* __restrict__ cnt, float* __restrict__ dvec,
                                              const float* __restrict__ X,
                                              __bf16* __restrict__ Xh, __bf16* __restrict__ Xl,
                                              const float* __restrict__ W,
                                              __bf16* __restrict__ WhT, __bf16* __restrict__ WlT) {
    int bid = blockIdx.x;
    if (bid < XS4_BLOCKS) {
        int e = (bid * 256 + threadIdx.x) * 4;        // 4 elems, same row (KP%4==0)
        int i = e / KP, c = e - i * KP;
        const float* xr = X + (size_t)i * FIN + c;
        float x0 = (c + 0 < FIN) ? xr[0] : 0.f;
        float x1 = (c + 1 < FIN) ? xr[1] : 0.f;
        float x2 = (c + 2 < FIN) ? xr[2] : 0.f;
        float x3 = (c + 3 < FIN) ? xr[3] : 0.f;
        __bf16 h0 = (__bf16)x0, h1 = (__bf16)x1, h2 = (__bf16)x2, h3 = (__bf16)x3;
        bf16x4 hv = {h0, h1, h2, h3};
        bf16x4 lv = {(__bf16)(x0 - (float)h0), (__bf16)(x1 - (float)h1),
                     (__bf16)(x2 - (float)h2), (__bf16)(x3 - (float)h3)};
        *(bf16x4*)(Xh + e) = hv;
        *(bf16x4*)(Xl + e) = lv;
        return;
    }
    bid -= XS4_BLOCKS;
    if (bid < WSPLIT_BLOCKS) {
        int idx = bid * 256 + threadIdx.x;
        int c = idx / KP, k = idx - c * KP;
        float x = (k < FIN) ? W[(size_t)k * 256 + c] : 0.f;
        __bf16 h = (__bf16)x;
        WhT[idx] = h;
        WlT[idx] = (__bf16)(x - (float)h);
        return;
    }
    bid -= WSPLIT_BLOCKS;
    int i = bid * 4 + (threadIdx.x >> 6);
    int lane = threadIdx.x & 63;
    const float* row = adj + (size_t)i * NN;
    unsigned long long below = (1ull << lane) - 1ull;
    float s = 0.f; int count = 0;
    int base = i * MAXR;
    for (int c0 = 0; c0 < NN; c0 += 256) {
        float4 a4 = *(const float4*)(row + c0 + lane * 4);
        float a[4] = {a4.x, a4.y, a4.z, a4.w};
        s += a[0] + a[1] + a[2] + a[3];
        unsigned long long bal[4];
        #pragma unroll
        for (int u = 0; u < 4; u++) bal[u] = __ballot(a[u] != 0.f);
        int before = 0;
        #pragma unroll
        for (int u = 0; u < 4; u++) before += __popcll(bal[u] & below);
        int local = 0;
        #pragma unroll
        for (int u = 0; u < 4; u++) {
            if (a[u] != 0.f) {
                int pos = count + before + local;
                if (pos < MAXR) { cols[base + pos] = c0 + lane * 4 + u; vals[base + pos] = a[u]; }
                local++;
            }
        }
        int tot = 0;
        #pragma unroll
        for (int u = 0; u < 4; u++) tot += __popcll(bal[u]);
        count += tot;
    }
    for (int off = 32; off; off >>= 1) s += __shfl_xor(s, off);
    if (lane == 0) {
        cnt[i] = count < MAXR ? count : MAXR;
        dvec[i] = (s > 0.f) ? 1.0f / sqrtf(s) : 0.f;
    }
}

// ---- fc1 MFMA: 64x64 tile, 4 waves, split-K (R19-measured config) ----
__global__ __launch_bounds__(256) void fc1m_k(const __bf16* __restrict__ Xh,
                                              const __bf16* __restrict__ Xl,
                                              const __bf16* __restrict__ WhT,
                                              const __bf16* __restrict__ WlT,
                                              float* __restrict__ Cpart) {
    int tid = threadIdx.x;
    int w = tid >> 6, lane = tid & 63;
    int m = lane & 15, q = lane >> 4;
    int i0 = blockIdx.x * 64, c0 = blockIdx.y * 64;
    int z = blockIdx.z;
    int k0 = z * KSLICE;
    int rowA = i0 + w * 16 + m;
    const __bf16* xh = Xh + (size_t)rowA * KP + k0 + q * 8;
    const __bf16* xl = Xl + (size_t)rowA * KP + k0 + q * 8;
    const __bf16* bh0 = WhT + (size_t)(c0 + m) * KP + k0 + q * 8;
    const __bf16* bl0 = WlT + (size_t)(c0 + m) * KP + k0 + q * 8;

    f32x4 acc[4];
    #pragma unroll
    for (int ct = 0; ct < 4; ct++)
        #pragma unroll
        for (int r = 0; r < 4; r++) acc[ct][r] = 0.f;

    for (int ks = 0; ks < KSLICE; ks += 32) {
        bf16x8 ah = *(const bf16x8*)(xh + ks);
        bf16x8 al = *(const bf16x8*)(xl + ks);
        #pragma unroll
        for (int ct = 0; ct < 4; ct++) {
            bf16x8 bh = *(const bf16x8*)(bh0 + (size_t)ct * 16 * KP + ks);
            bf16x8 bl = *(const bf16x8*)(bl0 + (size_t)ct * 16 * KP + ks);
            acc[ct] = __builtin_amdgcn_mfma_f32_16x16x32_bf16(ah, bh, acc[ct], 0, 0, 0);
            acc[ct] = __builtin_amdgcn_mfma_f32_16x16x32_bf16(ah, bl, acc[ct], 0, 0, 0);
            acc[ct] = __builtin_amdgcn_mfma_f32_16x16x32_bf16(al, bh, acc[ct], 0, 0, 0);
        }
    }
    float* outp = Cpart + (size_t)z * NN * 256;
    int rowBase = i0 + w * 16 + q * 4;
    #pragma unroll
    for (int ct = 0; ct < 4; ct++) {
        int col = c0 + ct * 16 + m;
        #pragma unroll
        for (int r = 0; r < 4; r++)
            outp[(size_t)(rowBase + r) * 256 + col] = acc[ct][r];
    }
}

// ---- merged: y=0,1 threshold masks; y=2 An^2 sparse x sparse; y=3 fc1 reduce ----
__global__ __launch_bounds__(256) void maskall_k(const int* __restrict__ cols,
                                                 const float* __restrict__ vals,
                                                 const int* __restrict__ cnt,
                                                 const float* __restrict__ dvec,
                                                 const float* __restrict__ thrp,
                                                 int* __restrict__ mcols,
                                                 float* __restrict__ mvals,
                                                 int* __restrict__ mcnt,
                                                 float* __restrict__ db,
                                                 const float* __restrict__ Cpart,
                                                 const float* __restrict__ bias,
                                                 float* __restrict__ X0) {
    __shared__ float ds[NN];
    __shared__ int lcols[MAXR];
    __shared__ float lvals[MAXR];
    __shared__ int lcnt;
    __shared__ float osum;
    int i = blockIdx.x, tid = threadIdx.x, mode = blockIdx.y;

    if (mode == 3) {
        // fc1 split-K reduce + bias + relu: row i, 64 float4s
        if (tid < 64) {
            int idx4 = i * 64 + tid;
            int c4 = tid << 2;
            float4 s = ((const float4*)Cpart)[idx4];
            #pragma unroll
            for (int z = 1; z < KSPLIT; z++) {
                float4 t = ((const float4*)(Cpart + (size_t)z * NN * 256))[idx4];
                s.x += t.x; s.y += t.y; s.z += t.z; s.w += t.w;
            }
            float4 b = *(const float4*)&bias[c4];
            s.x = fmaxf(s.x + b.x, 0.f); s.y = fmaxf(s.y + b.y, 0.f);
            s.z = fmaxf(s.z + b.z, 0.f); s.w = fmaxf(s.w + b.w, 0.f);
            ((float4*)X0)[idx4] = s;
        }
        return;
    }

    mcols += (size_t)mode * NN * MAXR;
    mvals += (size_t)mode * NN * MAXR;
    mcnt  += (size_t)mode * NN;
    db    += (size_t)mode * NN;
    int ni = cnt[i], base = i * MAXR;
    float thr = *thrp;
    float di = dvec[i];

    if (mode < 2) {
        if (tid == 0) lcnt = 0;
        __syncthreads();
        float s = 0.f;
        if (tid < ni) {
            int j = cols[base + tid];
            float a = vals[base + tid];
            float m = (mode == 0) ? a : a * di * dvec[j];
            if (m > thr) {
                int p = atomicAdd(&lcnt, 1);
                mcols[base + p] = j;
                mvals[base + p] = a;
                s = a;
            }
        }
        ds[tid] = s; __syncthreads();
        for (int off = 128; off; off >>= 1) {
            if (tid < off) ds[tid] += ds[tid + off];
            __syncthreads();
        }
        if (tid == 0) {
            mcnt[i] = lcnt;
            db[i] = 1.0f / sqrtf(ds[0] + 1.0f);
        }
        return;
    }

    if (tid == 0) { osum = 0.f; lcnt = 0; }
    for (int j = tid; j < NN; j += 256) ds[j] = 0.f;
    __syncthreads();
    for (int t = tid; t < ni; t += 256) {
        int j = cols[base + t];
        float a = vals[base + t];
        lcols[t] = j; lvals[t] = a;
        ds[j] = a * dvec[j] * dvec[j];
    }
    __syncthreads();
    int lane = tid & 63, wv = tid >> 6;
    int sub = lane & 15, dg = lane >> 4;      // 16-lane subgroup, 4 dots/wave in flight
    for (int o = wv * 4 + dg; o < ni; o += 16) {
        int j = lcols[o];
        int nj = cnt[j], bj = j * MAXR;
        float dot = 0.f;
        for (int t = sub; t < nj; t += 16)
            dot += vals[bj + t] * ds[cols[bj + t]];
        #pragma unroll
        for (int off = 8; off; off >>= 1) dot += __shfl_xor(dot, off);
        if (sub == 0 && di * dvec[j] * dot > thr) {
            int p = atomicAdd(&lcnt, 1);
            mcols[base + p] = j;
            mvals[base + p] = lvals[o];
            atomicAdd(&osum, lvals[o]);
        }
    }
    __syncthreads();
    if (tid == 0) {
        mcnt[i] = lcnt;
        db[i] = 1.0f / sqrtf(osum + 1.0f);
    }
}

// ---- branch-batched GEMM: 64x64 tile, 4x4/thread; z = branch; N=128 ----
__global__ __launch_bounds__(256) void gemm3_k(const float* __restrict__ A, int aplane, int lda,
                                               const float* __restrict__ B0,
                                               const float* __restrict__ B1,
                                               const float* __restrict__ B2,
                                               int K, float* __restrict__ out) {
    __shared__ float Ast[16][68];
    __shared__ float Bs[16][64];
    int tid = threadIdx.x;
    int tx = tid & 15, ty = tid >> 4;
    int i0 = blockIdx.x * 64, c0 = blockIdx.y * 64;
    int z = blockIdx.z;
    const float* Ab = A + (size_t)z * aplane;
    const float* B = (z == 0) ? B0 : (z == 1) ? B1 : B2;
    float* outp = out + (size_t)z * NN * 128;
    int sr = tid >> 4, sk = tid & 15;
    int bk = tid >> 4, bc4 = (tid & 15) << 2;

    float ap[4]; float4 bp;
    #pragma unroll
    for (int u = 0; u < 4; u++) ap[u] = Ab[(size_t)(i0 + sr + u * 16) * lda + sk];
    bp = *(const float4*)&B[(size_t)bk * 128 + c0 + bc4];

    float acc[4][4];
    #pragma unroll
    for (int r = 0; r < 4; r++)
        #pragma unroll
        for (int c = 0; c < 4; c++) acc[r][c] = 0.f;

    for (int kt = 0; kt < K; kt += 16) {
        __syncthreads();
        #pragma unroll
        for (int u = 0; u < 4; u++) Ast[sk][sr + u * 16] = ap[u];
        *(float4*)&Bs[bk][bc4] = bp;
        __syncthreads();
        int kn = kt + 16;
        if (kn < K) {
            #pragma unroll
            for (int u = 0; u < 4; u++) ap[u] = Ab[(size_t)(i0 + sr + u * 16) * lda + kn + sk];
            bp = *(const float4*)&B[(size_t)(kn + bk) * 128 + c0 + bc4];
        }
        #pragma unroll
        for (int kk = 0; kk < 16; kk++) {
            float4 a = *(const float4*)&Ast[kk][ty * 4];
            float4 b = *(const float4*)&Bs[kk][tx * 4];
            const float* av = (const float*)&a;
            const float* bv = (const float*)&b;
            #pragma unroll
            for (int r = 0; r < 4; r++)
                #pragma unroll
                for (int c = 0; c < 4; c++) acc[r][c] += av[r] * bv[c];
        }
    }
    #pragma unroll
    for (int r = 0; r < 4; r++) {
        int row = i0 + ty * 4 + r;
        float4 v = make_float4(acc[r][0], acc[r][1], acc[r][2], acc[r][3]);
        *(float4*)&outp[(size_t)row * 128 + c0 + tx * 4] = v;
    }
}

// ---- SpMM: masked CSR, float4 gather, 8-way t-parallel ----
__global__ __launch_bounds__(256) void spmm3_k(const int* __restrict__ mcols,
                                               const float* __restrict__ mvals,
                                               const int* __restrict__ mcnt,
                                               const float* __restrict__ db,
                                               const float* __restrict__ Xin,   // [3][NN][128]
                                               const float* __restrict__ bias0,
                                               const float* __restrict__ bias1,
                                               const float* __restrict__ bias2,
                                               float* __restrict__ outA,        // [3][NN][128] or null
                                               float* __restrict__ embf, int coff) {
    __shared__ float lcoef[MAXR];
    __shared__ int lj[MAXR];
    __shared__ float4 part[8][32];
    int i = blockIdx.x, tid = threadIdx.x, b = blockIdx.y;
    mcols += (size_t)b * NN * MAXR;
    mvals += (size_t)b * NN * MAXR;
    mcnt  += (size_t)b * NN;
    db    += (size_t)b * NN;
    const float* Xb = Xin + (size_t)b * NN * 128;
    const float* bias = (b == 0) ? bias0 : (b == 1) ? bias1 : bias2;
    float dbi = db[i];
    int n = mcnt[i], base = i * MAXR;
    if (tid < n) {
        int j = mcols[base + tid];
        lj[tid] = j;
        lcoef[tid] = mvals[base + tid] * dbi * db[j];
    }
    __syncthreads();
    int g = tid >> 5, c4 = (tid & 31) << 2;
    float4 acc = make_float4(0.f, 0.f, 0.f, 0.f);
    if (g == 0) {
        float4 x = *(const float4*)&Xb[(size_t)i * 128 + c4];
        float d2 = dbi * dbi;
        acc = make_float4(d2 * x.x, d2 * x.y, d2 * x.z, d2 * x.w);
    }
    for (int t = g; t < n; t += 8) {
        float cf = lcoef[t];
        float4 x = *(const float4*)&Xb[(size_t)lj[t] * 128 + c4];
        acc.x += cf * x.x; acc.y += cf * x.y; acc.z += cf * x.z; acc.w += cf * x.w;
    }
    part[g][tid & 31] = acc;
    __syncthreads();
    if (tid < 32) {
        float4 s = part[0][tid];
        #pragma unroll
        for (int gg = 1; gg < 8; gg++) {
            float4 t4 = part[gg][tid];
            s.x += t4.x; s.y += t4.y; s.z += t4.z; s.w += t4.w;
        }
        int cc = tid << 2;
        float4 bv = *(const float4*)&bias[cc];
        s.x = fmaxf(s.x + bv.x, 0.f); s.y = fmaxf(s.y + bv.y, 0.f);
        s.z = fmaxf(s.z + bv.z, 0.f); s.w = fmaxf(s.w + bv.w, 0.f);
        if (outA) *(float4*)&outA[((size_t)b * NN + i) * 128 + cc] = s;
        *(float4*)&embf[((size_t)b * NN + i) * 256 + coff + cc] = s;
    }
}

// ---- dilated 3x3 conv: LDS-staged rows, one block per output row n ----
__global__ __launch_bounds__(256) void conv3f_k(const float* __restrict__ emb,
                                                const float* __restrict__ ck,
                                                const float* __restrict__ cb,
                                                float* __restrict__ outf) {
    __shared__ float rows[3][3][256];
    int n = blockIdx.x, c = threadIdx.x;
    #pragma unroll
    for (int i = 0; i < 3; i++)
        #pragma unroll
        for (int kh = 0; kh < 3; kh++) {
            int nn2 = n + 2 * kh - 2;
            rows[i][kh][c] = (nn2 >= 0 && nn2 < NN) ? emb[((size_t)i * NN + nn2) * 256 + c] : 0.f;
        }
    __syncthreads();
    float s = cb[0];
    #pragma unroll
    for (int i = 0; i < 3; i++)
        #pragma unroll
        for (int kh = 0; kh < 3; kh++)
            #pragma unroll
            for (int kw = 0; kw < 3; kw++) {
                int cc = c + 2 * kw - 2;
                if (cc >= 0 && cc < 256)
                    s += rows[i][kh][cc] * ck[(i * 3 + kh) * 3 + kw];
            }
    outf[(size_t)n * 256 + c] = s;
}

// ---- uv GEMM: uv[node][c] c<64: emb.Wa_left ; c>=64: emb.Wa_right. K-split 2 planes ----
__global__ __launch_bounds__(256) void gemmUV_k(const float* __restrict__ A,   // [NN][256] emb_all
                                                const float* __restrict__ Wa,  // [512][64]
                                                float* __restrict__ uvp) {     // [2][NN][128]
    __shared__ float Ast[16][68];
    __shared__ float Bs[16][64];
    int tid = threadIdx.x;
    int tx = tid & 15, ty = tid >> 4;
    int i0 = blockIdx.x * 64;
    int half = blockIdx.y;
    int z = blockIdx.z;
    int ks = z * 128;
    const float* Bb = Wa + (half ? 256 * 64 : 0);
    int sr = tid >> 4, sk = tid & 15;
    int bk = tid >> 4, bc4 = (tid & 15) << 2;

    float ap[4]; float4 bp;
    #pragma unroll
    for (int u = 0; u < 4; u++) ap[u] = A[(size_t)(i0 + sr + u * 16) * 256 + ks + sk];
    bp = *(const float4*)&Bb[(size_t)(ks + bk) * 64 + bc4];

    float acc[4][4];
    #pragma unroll
    for (int r = 0; r < 4; r++)
        #pragma unroll
        for (int c = 0; c < 4; c++) acc[r][c] = 0.f;

    for (int kt = ks; kt < ks + 128; kt += 16) {
        __syncthreads();
        #pragma unroll
        for (int u = 0; u < 4; u++) Ast[sk][sr + u * 16] = ap[u];
        *(float4*)&Bs[bk][bc4] = bp;
        __syncthreads();
        int kn = kt + 16;
        if (kn < ks + 128) {
            #pragma unroll
            for (int u = 0; u < 4; u++) ap[u] = A[(size_t)(i0 + sr + u * 16) * 256 + kn + sk];
            bp = *(const float4*)&Bb[(size_t)(kn + bk) * 64 + bc4];
        }
        #pragma unroll
        for (int kk = 0; kk < 16; kk++) {
            float4 a = *(const float4*)&Ast[kk][ty * 4];
            float4 b = *(const float4*)&Bs[kk][tx * 4];
            const float* av = (const float*)&a;
            const float* bv = (const float*)&b;
            #pragma unroll
            for (int r = 0; r < 4; r++)
                #pragma unroll
                for (int c = 0; c < 4; c++) acc[r][c] += av[r] * bv[c];
        }
    }
    float* outp = uvp + (size_t)z * NN * 128;
    #pragma unroll
    for (int r = 0; r < 4; r++) {
        int row = i0 + ty * 4 + r;
        float4 v = make_float4(acc[r][0], acc[r][1], acc[r][2], acc[r][3]);
        *(float4*)&outp[(size_t)row * 128 + half * 64 + tx * 4] = v;
    }
}

// ---- pair gather + logits: 16 pairs/block, 4 per wave ----
__global__ __launch_bounds__(256) void pairuv_k(const int* __restrict__ left,
                                                const int* __restrict__ right,
                                                const float* __restrict__ uvp,
                                                const float* __restrict__ ba,
                                                const float* __restrict__ Wb,
                                                const float* __restrict__ bb,
                                                float* __restrict__ out) {
    int tid = threadIdx.x;
    int w = tid >> 6, c = tid & 63;
    int base = blockIdx.x * 16 + w * 4;
    const float* u0 = uvp;
    const float* u1 = uvp + (size_t)NN * 128;
    float bac = ba[c];
    float w0 = Wb[c * 2], w1 = Wb[c * 2 + 1];
    float b0 = bb[0], b1 = bb[1];
    #pragma unroll
    for (int pp = 0; pp < 4; pp++) {
        int row = base + pp;
        int l = left[row], r = right[row];
        float h = u0[(size_t)l * 128 + c] + u1[(size_t)l * 128 + c]
                + u0[(size_t)r * 128 + 64 + c] + u1[(size_t)r * 128 + 64 + c] + bac;
        h = fmaxf(h, 0.f);
        float s0 = h * w0, s1 = h * w1;
        for (int off = 32; off; off >>= 1) {
            s0 += __shfl_xor(s0, off);
            s1 += __shfl_xor(s1, off);
        }
        if (c == 0) {
            out[row * 2]     = s0 + b0;
            out[row * 2 + 1] = s1 + b1;
        }
    }
}

extern "C" void kernel_launch(void* const* d_in, const int* in_sizes, int n_in,
                              void* d_out, int out_size, void* d_ws, size_t ws_size,
                              hipStream_t stream) {
    const int* left  = (const int*)d_in[0];
    const int* right = (const int*)d_in[1];
    const float* X    = (const float*)d_in[2];
    const float* adj  = (const float*)d_in[3];
    const float* thr  = (const float*)d_in[4];
    const float* Wfc1 = (const float*)d_in[5];
    const float* bfc1 = (const float*)d_in[6];
    // channel order b0,b1,b2 = (adj mask, Wg5/6), (An mask, Wg3/4), (An^2 mask, Wg1/2)
    const float* Wga[3] = { (const float*)d_in[15], (const float*)d_in[11], (const float*)d_in[7] };
    const float* bga[3] = { (const float*)d_in[16], (const float*)d_in[12], (const float*)d_in[8] };
    const float* Wgb[3] = { (const float*)d_in[17], (const float*)d_in[13], (const float*)d_in[9] };
    const float* bgb[3] = { (const float*)d_in[18], (const float*)d_in[14], (const float*)d_in[10] };
    const float* cnnk = (const float*)d_in[19];
    const float* cnnb = (const float*)d_in[20];
    const float* Wa_  = (const float*)d_in[21];
    const float* ba_  = (const float*)d_in[22];
    const float* Wb_  = (const float*)d_in[23];
    const float* bb_  = (const float*)d_in[24];

    char* p = (char*)d_ws;
    auto take = [&](size_t n) { char* q = p; p += (n + 255) & ~(size_t)255; return q; };
    float* dvec = (float*)take(NN * 4);
    float* db3  = (float*)take((size_t)3 * NN * 4);
    int*   cnt  = (int*)take(NN * 4);
    int*   mcnt3 = (int*)take((size_t)3 * NN * 4);
    int*   cols = (int*)take((size_t)NN * MAXR * 4);
    float* vals = (float*)take((size_t)NN * MAXR * 4);
    int*   mcols3 = (int*)take((size_t)3 * NN * MAXR * 4);    // 7.1 MB (contiguous with mvals3)
    float* mvals3 = (float*)take((size_t)3 * NN * MAXR * 4);  // 7.1 MB
    float* X0    = (float*)take((size_t)NN * 256 * 4);
    float* XWall = (float*)take((size_t)3 * NN * 128 * 4);
    float* e1all = (float*)take((size_t)3 * NN * 128 * 4);
    float* HW2all= (float*)take((size_t)3 * NN * 128 * 4);
    float* embf  = (float*)take((size_t)3 * NN * 256 * 4);
    __bf16* Xl   = (__bf16*)take((size_t)NN * KP * 2);        // 9.6 MB
    __bf16* WhT  = (__bf16*)take((size_t)256 * KP * 2);       // 0.8 MB
    __bf16* WlT  = (__bf16*)take((size_t)256 * KP * 2);       // 0.8 MB
    // Xh (9.6 MB) aliases mcols3+mvals3 (14.2 MB contiguous): dead once fc1m completes,
    // before maskall_k writes mcols3/mvals3.
    __bf16* Xh = (__bf16*)mcols3;
    // Cpart: KSPLIT(=7) planes of NN*256 f32 = 22.0 MB aliasing XWall..embf (23.6 MB);
    // consumed by maskall_k (y=3 reduce lane) before XWall/e1all/HW2all/embf are written.
    float* Cpart = XWall;
    // uvp: 2 planes of NN*128 f32 = 3.1 MB aliasing embf (dead after conv3f_k).
    float* uvp = embf;

    float* out_logits = (float*)d_out;
    float* out_emb = out_logits + 32768;

    // fused prep: xsplit (x4 ILP) + wsplit + csr build (float4 + ballot4)
    prep_k<<<XS4_BLOCKS + WSPLIT_BLOCKS + CSR_BLOCKS, 256, 0, stream>>>(
        adj, cols, vals, cnt, dvec, X, Xh, Xl, Wfc1, WhT, WlT);

    // fc1: X0 = relu(X @ Wfc1 + b), MFMA split-K (reduce folded into maskall y=3)
    fc1m_k<<<dim3(NN / 64, 4, KSPLIT), 256, 0, stream>>>(Xh, Xl, WhT, WlT, Cpart);

    // masks (y=0,1 light; y=2 heavy M2) + fc1 reduce (y=3) in one dispatch
    maskall_k<<<dim3(NN, 4), 256, 0, stream>>>(cols, vals, cnt, dvec, thr,
                                               mcols3, mvals3, mcnt3, db3,
                                               Cpart, bfc1, X0);

    // XW[b] = X0 @ Wga[b]
    gemm3_k<<<dim3(NN / 64, 2, 3), 256, 0, stream>>>(X0, 0, 256, Wga[0], Wga[1], Wga[2], 256, XWall);
    // e1[b] = relu(An_b @ XW[b] + bga[b]) -> e1all + embf cols 0..127
    spmm3_k<<<dim3(NN, 3), 256, 0, stream>>>(mcols3, mvals3, mcnt3, db3, XWall,
                                             bga[0], bga[1], bga[2], e1all, embf, 0);
    // HW2[b] = e1[b] @ Wgb[b]
    gemm3_k<<<dim3(NN / 64, 2, 3), 256, 0, stream>>>(e1all, NN * 128, 128, Wgb[0], Wgb[1], Wgb[2], 128, HW2all);
    // e2[b] = relu(An_b @ HW2[b] + bgb[b]) -> embf cols 128..255
    spmm3_k<<<dim3(NN, 3), 256, 0, stream>>>(mcols3, mvals3, mcnt3, db3, HW2all,
                                             bgb[0], bgb[1], bgb[2], (float*)0, embf, 128);

    conv3f_k<<<NN, 256, 0, stream>>>(embf, cnnk, cnnb, out_emb);
    // pair MLP via u/v decomposition: uv = emb_all @ [Wa_left | Wa_right]
    gemmUV_k<<<dim3(NN / 64, 2, 2), 256, 0, stream>>>(out_emb, Wa_, uvp);
    pairuv_k<<<16384 / 16, 256, 0, stream>>>(left, right, uvp, ba_, Wb_, bb_, out_logits);
}